// Round 19
// baseline (382.404 us; speedup 1.0000x reference)
//
#include <hip/hip_runtime.h>
#include <hip/hip_bf16.h>

typedef __attribute__((ext_vector_type(8))) short bf16x8;
typedef __attribute__((ext_vector_type(4))) float f32x4;
typedef __attribute__((ext_vector_type(4))) unsigned short u16x4;

__device__ __forceinline__ unsigned short f2bf(float f) {
    __hip_bfloat16 h = __float2bfloat16(f);   // RTNE; pairs fuse to v_cvt_pk_bf16_f32
    union { __hip_bfloat16 h; unsigned short u; } v; v.h = h;
    return v.u;
}

__device__ __forceinline__ void cp16_g2l(const void* g, void* l) {
    __builtin_amdgcn_global_load_lds(
        (const __attribute__((address_space(1))) unsigned int*)g,
        (__attribute__((address_space(3))) unsigned int*)l, 16, 0, 0);
}

// ---- one-time: W_h f32 [128][384] -> plain bf16 row-major image in ws ----
__global__ __launch_bounds__(384) void k_cvtW(const float* __restrict__ Wh,
                                              unsigned short* __restrict__ Wbf) {
    int n = blockIdx.x, k = threadIdx.x;
    Wbf[n * 384 + k] = f2bf(Wh[n * 384 + k]);
}

// =====================================================================
// Whole-tree kernel (r17 structure, G=1024 for 3 blocks/CU occupancy).
// 1024 blocks; block b owns rows [b*R_j,(b+1)*R_j) at every level,
// R_j = 1<<j (level 0: 1 row). Children of that slice are the block's
// OWN previous-level output -> no inter-block deps; levels separated by
// intra-block vmcnt(0)+barrier. Each level writes a DISJOINT ws region
// (offset 131072*(512-2^(j+1)) elems — G-independent).
// launch_bounds (512,6): 24 waves/CU (3 blocks x 52 KiB LDS); VGPR cap 80,
// current use 64 -> no spill expected.
// Transposed compute (thread owns 4 consecutive cols -> 8B writes),
// full-width &15 XOR swizzle, counted vmcnt(6) A-DMA pipeline.
// =====================================================================
__global__ __launch_bounds__(512, 6) void k_main(
    const float* __restrict__ c0, const float* __restrict__ c1,
    const float* __restrict__ c2, const float* __restrict__ c3,
    const float* __restrict__ c4, const float* __restrict__ c5,
    const float* __restrict__ c6, const float* __restrict__ c7,
    const float* __restrict__ c8, const float* __restrict__ c9,
    const unsigned short* __restrict__ Wbf,
    const float* __restrict__ Wu, const float* __restrict__ bu,
    const float* __restrict__ bh,
    unsigned short* __restrict__ tbase,
    float* __restrict__ outF)
{
    __shared__ __align__(16) unsigned short A_lds[2][64][128]; // [cc][il][n^swz16]
    __shared__ __align__(16) unsigned short u_lds[64][128];    // [i][n^swz16]
    __shared__ __align__(16) unsigned short wu_lds[8][32][8];

    const int t = threadIdx.x, lane = t & 63, wid = t >> 6;    // 8 waves
    const int l15 = lane & 15, l4 = lane >> 4;
    const int wrow = wid & 3;
    const int wcolh = wid >> 2;
    const int b = blockIdx.x;

    // ---- persistent W fragments: wave's 16-col slice (48 VGPR, pinned) ----
    bf16x8 wreg[12];
    {
        int n = wid * 16 + l15;
        #pragma unroll
        for (int kb = 0; kb < 12; ++kb)
            wreg[kb] = *reinterpret_cast<const bf16x8*>(Wbf + n * 384 + kb * 32 + l4 * 8);
    }
    #pragma unroll
    for (int kb = 0; kb < 12; ++kb)
        asm volatile("" : "+v"(wreg[kb]));

    if (wid == 0 && l4 < 2) {
        #pragma unroll
        for (int nf = 0; nf < 8; ++nf) {
            int n = nf * 16 + l15;
            bf16x8 v = {0, 0, 0, 0, 0, 0, 0, 0};
            if (l4 == 0) {
                #pragma unroll
                for (int k = 0; k < 8; ++k) ((unsigned short*)&v)[k] = f2bf(Wu[n * 8 + k]);
            } else {
                ((unsigned short*)&v)[0] = f2bf(bu[n]);
            }
            *(bf16x8*)&wu_lds[nf][l4 * 16 + l15][0] = v;
        }
    }
    const f32x4 bh4 = *(const f32x4*)&bh[wid * 16 + l4 * 4];

    bf16x8 zeroA = {0, 0, 0, 0, 0, 0, 0, 0};
    bf16x8 onesA = zeroA; ((unsigned short*)&onesA)[0] = 0x3F80;

    __syncthreads();  // wu_lds visible

    // region pointer for level j's emb output (G-independent)
    #define RG(j) (tbase + (size_t)131072 * (512 - (2 << (j))))

    f32x4 cO0 = {0,0,0,0}, cO1 = {0,0,0,0};

    // ================= LEVEL 8 (leaf): T=4 full tiles =================
    {
        const int T = 4;
        const int tb = b * T;
        unsigned short* eOut = RG(8);
        if (l4 == 0) {
            const float* p = c8 + ((size_t)tb * 64 + wrow * 16 + l15) * 8;
            cO0 = *(const f32x4*)p; cO1 = *(const f32x4*)(p + 4);
        }
        for (int tt = 0; tt < T; ++tt) {
            const int tile = tb + tt;
            // ---- u-phase ----
            {
                bf16x8 cb = zeroA;
                if (l4 == 0) {
                    #pragma unroll
                    for (int e = 0; e < 4; ++e) {
                        ((unsigned short*)&cb)[e]     = f2bf(cO0[e]);
                        ((unsigned short*)&cb)[e + 4] = f2bf(cO1[e]);
                    }
                } else if (l4 == 1) cb = onesA;
                const int i = wrow * 16 + l15;
                #pragma unroll
                for (int nfi = 0; nfi < 4; ++nfi) {
                    int nf = wcolh * 4 + nfi;
                    bf16x8 wv = zeroA;
                    if (l4 < 2) wv = *(const bf16x8*)&wu_lds[nf][l4 * 16 + l15][0];
                    f32x4 z = {0.f, 0.f, 0.f, 0.f};
                    z = __builtin_amdgcn_mfma_f32_16x16x32_bf16(wv, cb, z, 0, 0, 0);
                    u16x4 pk;
                    #pragma unroll
                    for (int r = 0; r < 4; ++r) pk[r] = f2bf(fmaxf(z[r], 0.f));
                    int n4 = nf * 16 + l4 * 4;
                    *(u16x4*)&u_lds[i][n4 ^ ((i & 15) << 3)] = pk;
                }
            }
            // ---- child-u: direct loads from c9 ----
            {
                const float* pcBase = c9 + ((size_t)tile * 128 + wrow * 32 + l15) * 8;
                #pragma unroll
                for (int rb = 0; rb < 2; ++rb) {
                    bf16x8 cb = zeroA;
                    if (l4 == 0) {
                        f32x4 a  = *(const f32x4*)(pcBase + rb * 128);
                        f32x4 b2 = *(const f32x4*)(pcBase + rb * 128 + 4);
                        #pragma unroll
                        for (int e = 0; e < 4; ++e) {
                            ((unsigned short*)&cb)[e]     = f2bf(a[e]);
                            ((unsigned short*)&cb)[e + 4] = f2bf(b2[e]);
                        }
                    } else if (l4 == 1) cb = onesA;
                    const int rr = wrow * 32 + rb * 16 + l15;
                    const int cc = rr & 1, il = rr >> 1;
                    #pragma unroll
                    for (int nfi = 0; nfi < 4; ++nfi) {
                        int nf = wcolh * 4 + nfi;
                        bf16x8 wv = zeroA;
                        if (l4 < 2) wv = *(const bf16x8*)&wu_lds[nf][l4 * 16 + l15][0];
                        f32x4 z = {0.f, 0.f, 0.f, 0.f};
                        z = __builtin_amdgcn_mfma_f32_16x16x32_bf16(wv, cb, z, 0, 0, 0);
                        u16x4 pk;
                        #pragma unroll
                        for (int r = 0; r < 4; ++r) pk[r] = f2bf(fmaxf(z[r], 0.f));
                        int n4 = nf * 16 + l4 * 4;
                        *(u16x4*)&A_lds[cc][il][n4 ^ ((il & 15) << 3)] = pk;
                    }
                }
            }
            // ---- prefetch next tile's contents (clamped) ----
            {
                int tn = (tt + 1 < T) ? tile + 1 : tile;
                if (l4 == 0) {
                    const float* p = c8 + ((size_t)tn * 64 + wrow * 16 + l15) * 8;
                    cO0 = *(const f32x4*)p; cO1 = *(const f32x4*)(p + 4);
                }
            }
            asm volatile("s_waitcnt lgkmcnt(0)" ::: "memory");
            __builtin_amdgcn_sched_barrier(0);
            __builtin_amdgcn_s_barrier();
            __builtin_amdgcn_sched_barrier(0);

            f32x4 acc[4];
            #pragma unroll
            for (int mf = 0; mf < 4; ++mf) acc[mf] = bh4;
            #pragma unroll
            for (int kb = 0; kb < 8; ++kb) {
                bf16x8 af[4];
                #pragma unroll
                for (int mf = 0; mf < 4; ++mf) {
                    int i = mf * 16 + l15;
                    af[mf] = *(const bf16x8*)&A_lds[kb >> 2][i][((((kb & 3) * 4) + l4) ^ (i & 15)) * 8];
                }
                #pragma unroll
                for (int mf = 0; mf < 4; ++mf)
                    acc[mf] = __builtin_amdgcn_mfma_f32_16x16x32_bf16(wreg[kb], af[mf], acc[mf], 0, 0, 0);
            }
            #pragma unroll
            for (int kb = 8; kb < 12; ++kb) {
                bf16x8 af[4];
                #pragma unroll
                for (int mf = 0; mf < 4; ++mf) {
                    int i = mf * 16 + l15;
                    af[mf] = *(const bf16x8*)&u_lds[i][((((kb - 8) * 4) + l4) ^ (i & 15)) * 8];
                }
                #pragma unroll
                for (int mf = 0; mf < 4; ++mf)
                    acc[mf] = __builtin_amdgcn_mfma_f32_16x16x32_bf16(wreg[kb], af[mf], acc[mf], 0, 0, 0);
            }
            #pragma unroll
            for (int mf = 0; mf < 4; ++mf) {
                int i = mf * 16 + l15;
                int Rg = tile * 64 + i;
                int rr = Rg & 127, cc = rr & 1, il = rr >> 1;
                u16x4 pk;
                #pragma unroll
                for (int r = 0; r < 4; ++r) pk[r] = f2bf(fmaxf(acc[mf][r], 0.f));
                int n4 = wid * 16 + l4 * 4;
                *(u16x4*)&eOut[(size_t)(Rg >> 7) * 16384 + cc * 8192 + il * 128
                               + (n4 ^ ((il & 15) << 3))] = pk;
            }
            asm volatile("s_waitcnt lgkmcnt(0)" ::: "memory");
            __builtin_amdgcn_sched_barrier(0);
            __builtin_amdgcn_s_barrier();
        }
        asm volatile("s_waitcnt vmcnt(0) lgkmcnt(0)" ::: "memory");
        __builtin_amdgcn_sched_barrier(0);
        __builtin_amdgcn_s_barrier();
    }

    // ================= LEVELS 7..6: full-tile DMA levels =================
    for (int j = 7; j >= 6; --j) {
        const int T = 1 << (j - 6);     // 2, 1
        const int tb = b * T;
        const float* contO = (j == 7) ? c7 : c6;
        const unsigned short* eIn = RG(j + 1);
        unsigned short* eOut = RG(j);

        {
            const unsigned short* src = eIn + (size_t)tb * 16384;
            #pragma unroll
            for (int it = 0; it < 4; ++it) {
                int q = t + it * 512;
                cp16_g2l(src + q * 8, &A_lds[0][0][0] + q * 8);
            }
            if (l4 == 0) {
                const float* p = contO + ((size_t)tb * 64 + wrow * 16 + l15) * 8;
                cO0 = *(const f32x4*)p; cO1 = *(const f32x4*)(p + 4);
            }
        }
        __syncthreads();

        for (int tt = 0; tt < T; ++tt) {
            const int tile = tb + tt;
            {
                bf16x8 cb = zeroA;
                if (l4 == 0) {
                    #pragma unroll
                    for (int e = 0; e < 4; ++e) {
                        ((unsigned short*)&cb)[e]     = f2bf(cO0[e]);
                        ((unsigned short*)&cb)[e + 4] = f2bf(cO1[e]);
                    }
                } else if (l4 == 1) cb = onesA;
                const int i = wrow * 16 + l15;
                #pragma unroll
                for (int nfi = 0; nfi < 4; ++nfi) {
                    int nf = wcolh * 4 + nfi;
                    bf16x8 wv = zeroA;
                    if (l4 < 2) wv = *(const bf16x8*)&wu_lds[nf][l4 * 16 + l15][0];
                    f32x4 z = {0.f, 0.f, 0.f, 0.f};
                    z = __builtin_amdgcn_mfma_f32_16x16x32_bf16(wv, cb, z, 0, 0, 0);
                    u16x4 pk;
                    #pragma unroll
                    for (int r = 0; r < 4; ++r) pk[r] = f2bf(fmaxf(z[r], 0.f));
                    int n4 = nf * 16 + l4 * 4;
                    *(u16x4*)&u_lds[i][n4 ^ ((i & 15) << 3)] = pk;
                }
            }
            {
                int tn = (tt + 1 < T) ? tile + 1 : tile;
                if (l4 == 0) {
                    const float* p = contO + ((size_t)tn * 64 + wrow * 16 + l15) * 8;
                    cO0 = *(const f32x4*)p; cO1 = *(const f32x4*)(p + 4);
                }
            }
            asm volatile("s_waitcnt vmcnt(6)" ::: "memory");  // drain 4 DMA; leave 4 stores + 2 loads
            asm volatile("s_waitcnt lgkmcnt(0)" ::: "memory");
            __builtin_amdgcn_sched_barrier(0);
            __builtin_amdgcn_s_barrier();
            __builtin_amdgcn_sched_barrier(0);

            f32x4 acc[4];
            #pragma unroll
            for (int mf = 0; mf < 4; ++mf) acc[mf] = bh4;
            #pragma unroll
            for (int kb = 0; kb < 8; ++kb) {
                bf16x8 af[4];
                #pragma unroll
                for (int mf = 0; mf < 4; ++mf) {
                    int i = mf * 16 + l15;
                    af[mf] = *(const bf16x8*)&A_lds[kb >> 2][i][((((kb & 3) * 4) + l4) ^ (i & 15)) * 8];
                }
                #pragma unroll
                for (int mf = 0; mf < 4; ++mf)
                    acc[mf] = __builtin_amdgcn_mfma_f32_16x16x32_bf16(wreg[kb], af[mf], acc[mf], 0, 0, 0);
            }
            asm volatile("s_waitcnt lgkmcnt(0)" ::: "memory");
            __builtin_amdgcn_sched_barrier(0);
            __builtin_amdgcn_s_barrier();
            __builtin_amdgcn_sched_barrier(0);
            if (tt + 1 < T) {
                const unsigned short* src = eIn + (size_t)(tile + 1) * 16384;
                #pragma unroll
                for (int it = 0; it < 4; ++it) {
                    int q = t + it * 512;
                    cp16_g2l(src + q * 8, &A_lds[0][0][0] + q * 8);
                }
            }
            #pragma unroll
            for (int kb = 8; kb < 12; ++kb) {
                bf16x8 af[4];
                #pragma unroll
                for (int mf = 0; mf < 4; ++mf) {
                    int i = mf * 16 + l15;
                    af[mf] = *(const bf16x8*)&u_lds[i][((((kb - 8) * 4) + l4) ^ (i & 15)) * 8];
                }
                #pragma unroll
                for (int mf = 0; mf < 4; ++mf)
                    acc[mf] = __builtin_amdgcn_mfma_f32_16x16x32_bf16(wreg[kb], af[mf], acc[mf], 0, 0, 0);
            }
            #pragma unroll
            for (int mf = 0; mf < 4; ++mf) {
                int i = mf * 16 + l15;
                int Rg = tile * 64 + i;
                int rr = Rg & 127, cc = rr & 1, il = rr >> 1;
                u16x4 pk;
                #pragma unroll
                for (int r = 0; r < 4; ++r) pk[r] = f2bf(fmaxf(acc[mf][r], 0.f));
                int n4 = wid * 16 + l4 * 4;
                *(u16x4*)&eOut[(size_t)(Rg >> 7) * 16384 + cc * 8192 + il * 128
                               + (n4 ^ ((il & 15) << 3))] = pk;
            }
            asm volatile("s_waitcnt lgkmcnt(0)" ::: "memory");
            __builtin_amdgcn_sched_barrier(0);
            __builtin_amdgcn_s_barrier();
        }
        asm volatile("s_waitcnt vmcnt(0) lgkmcnt(0)" ::: "memory");
        __builtin_amdgcn_sched_barrier(0);
        __builtin_amdgcn_s_barrier();
    }

    // ================= LEVELS 5..0: partial (reg-staged), R = 1<<j =================
    for (int j = 5; j >= 0; --j) {
        const int R = 1 << j;            // 32..1
        const float* contO = (j == 5) ? c5 : (j == 4) ? c4 : (j == 3) ? c3
                           : (j == 2) ? c2 : (j == 1) ? c1 : c0;
        const unsigned short* eIn = RG(j + 1);
        unsigned short* eOut = (j > 0) ? RG(j) : nullptr;

        const size_t rowBase  = (size_t)b * (size_t)R;
        const size_t crowBase = rowBase * 2;

        {
            const int ilBase = ((int)(crowBase & 127)) >> 1;
            const unsigned short* gb = eIn + (crowBase >> 7) * (size_t)16384
                                     + (size_t)ilBase * 128;
            const int per = R * 16;
            for (int q = t; q < 2 * per; q += 512) {
                int cc = (q >= per) ? 1 : 0;
                int qq = q - cc * per;
                int il = qq >> 4, slot = qq & 15;
                int kc  = slot ^ (il & 15);
                int src = kc ^ ((ilBase + il) & 15);
                bf16x8 v = *(const bf16x8*)(gb + (size_t)cc * 8192 + il * 128 + src * 8);
                *(bf16x8*)&A_lds[cc][il][slot * 8] = v;
            }
        }
        {
            f32x4 a0 = {0,0,0,0}, a1 = {0,0,0,0};
            if (l4 == 0) {
                size_t row = rowBase + (size_t)(wrow * 16 + l15);
                size_t mx = rowBase + R - 1; if (row > mx) row = mx;
                const float* p = contO + row * 8;
                a0 = *(const f32x4*)p; a1 = *(const f32x4*)(p + 4);
            }
            bf16x8 cb = zeroA;
            if (l4 == 0) {
                #pragma unroll
                for (int e = 0; e < 4; ++e) {
                    ((unsigned short*)&cb)[e]     = f2bf(a0[e]);
                    ((unsigned short*)&cb)[e + 4] = f2bf(a1[e]);
                }
            } else if (l4 == 1) cb = onesA;
            const int i = wrow * 16 + l15;
            #pragma unroll
            for (int nfi = 0; nfi < 4; ++nfi) {
                int nf = wcolh * 4 + nfi;
                bf16x8 wv = zeroA;
                if (l4 < 2) wv = *(const bf16x8*)&wu_lds[nf][l4 * 16 + l15][0];
                f32x4 z = {0.f, 0.f, 0.f, 0.f};
                z = __builtin_amdgcn_mfma_f32_16x16x32_bf16(wv, cb, z, 0, 0, 0);
                u16x4 pk;
                #pragma unroll
                for (int r = 0; r < 4; ++r) pk[r] = f2bf(fmaxf(z[r], 0.f));
                int n4 = nf * 16 + l4 * 4;
                *(u16x4*)&u_lds[i][n4 ^ ((i & 15) << 3)] = pk;
            }
        }
        asm volatile("s_waitcnt lgkmcnt(0)" ::: "memory");
        __builtin_amdgcn_sched_barrier(0);
        __builtin_amdgcn_s_barrier();
        __builtin_amdgcn_sched_barrier(0);

        f32x4 acc[4];
        #pragma unroll
        for (int mf = 0; mf < 4; ++mf) acc[mf] = bh4;
        #pragma unroll
        for (int kb = 0; kb < 8; ++kb) {
            bf16x8 af[4];
            #pragma unroll
            for (int mf = 0; mf < 4; ++mf) {
                int i = mf * 16 + l15;
                af[mf] = *(const bf16x8*)&A_lds[kb >> 2][i][((((kb & 3) * 4) + l4) ^ (i & 15)) * 8];
            }
            #pragma unroll
            for (int mf = 0; mf < 4; ++mf)
                acc[mf] = __builtin_amdgcn_mfma_f32_16x16x32_bf16(wreg[kb], af[mf], acc[mf], 0, 0, 0);
        }
        #pragma unroll
        for (int kb = 8; kb < 12; ++kb) {
            bf16x8 af[4];
            #pragma unroll
            for (int mf = 0; mf < 4; ++mf) {
                int i = mf * 16 + l15;
                af[mf] = *(const bf16x8*)&u_lds[i][((((kb - 8) * 4) + l4) ^ (i & 15)) * 8];
            }
            #pragma unroll
            for (int mf = 0; mf < 4; ++mf)
                acc[mf] = __builtin_amdgcn_mfma_f32_16x16x32_bf16(wreg[kb], af[mf], acc[mf], 0, 0, 0);
        }
        if (j == 0) {
            #pragma unroll
            for (int mf = 0; mf < 4; ++mf) {
                int i = mf * 16 + l15;
                if (i < R) {
                    f32x4 o;
                    #pragma unroll
                    for (int r = 0; r < 4; ++r) o[r] = fmaxf(acc[mf][r], 0.f);
                    *(f32x4*)&outF[(rowBase + i) * 128 + wid * 16 + l4 * 4] = o;
                }
            }
        } else {
            #pragma unroll
            for (int mf = 0; mf < 4; ++mf) {
                int i = mf * 16 + l15;
                if (i < R) {
                    size_t Rg = rowBase + i;
                    int rr = (int)(Rg & 127), cc = rr & 1, il = rr >> 1;
                    u16x4 pk;
                    #pragma unroll
                    for (int r = 0; r < 4; ++r) pk[r] = f2bf(fmaxf(acc[mf][r], 0.f));
                    int n4 = wid * 16 + l4 * 4;
                    *(u16x4*)&eOut[(Rg >> 7) * 16384 + cc * 8192 + il * 128
                                   + (n4 ^ ((il & 15) << 3))] = pk;
                }
            }
        }
        asm volatile("s_waitcnt vmcnt(0) lgkmcnt(0)" ::: "memory");
        __builtin_amdgcn_sched_barrier(0);
        __builtin_amdgcn_s_barrier();
    }
    #undef RG
}

extern "C" void kernel_launch(void* const* d_in, const int* in_sizes, int n_in,
                              void* d_out, int out_size, void* d_ws, size_t ws_size,
                              hipStream_t stream) {
    const float* c[10];
    for (int j = 0; j < 10; ++j) c[j] = (const float*)d_in[j];
    const float* Wu = (const float*)d_in[19];
    const float* bu = (const float*)d_in[20];
    const float* Wh = (const float*)d_in[21];
    const float* bh = (const float*)d_in[22];

    unsigned short* Wbf   = (unsigned short*)d_ws;                       // 96 KiB (1 MiB pad)
    unsigned short* tbase = (unsigned short*)((char*)d_ws + (1u << 20)); // per-level regions

    k_cvtW<<<128, 384, 0, stream>>>(Wh, Wbf);
    k_main<<<1024, 512, 0, stream>>>(c[0], c[1], c[2], c[3], c[4], c[5], c[6], c[7],
                                     c[8], c[9], Wbf, Wu, bu, bh, tbase, (float*)d_out);
}

// Round 20
// 155.985 us; speedup vs baseline: 2.4515x; 2.4515x over previous
//
#include <hip/hip_runtime.h>
#include <hip/hip_bf16.h>

typedef __attribute__((ext_vector_type(8))) short bf16x8;
typedef __attribute__((ext_vector_type(4))) float f32x4;
typedef __attribute__((ext_vector_type(4))) unsigned short u16x4;

__device__ __forceinline__ unsigned short f2bf(float f) {
    __hip_bfloat16 h = __float2bfloat16(f);   // RTNE; pairs fuse to v_cvt_pk_bf16_f32
    union { __hip_bfloat16 h; unsigned short u; } v; v.h = h;
    return v.u;
}

__device__ __forceinline__ void cp16_g2l(const void* g, void* l) {
    __builtin_amdgcn_global_load_lds(
        (const __attribute__((address_space(1))) unsigned int*)g,
        (__attribute__((address_space(3))) unsigned int*)l, 16, 0, 0);
}

// ---- one-time: W_h f32 [128][384] -> plain bf16 row-major image in ws ----
__global__ __launch_bounds__(384) void k_cvtW(const float* __restrict__ Wh,
                                              unsigned short* __restrict__ Wbf) {
    int n = blockIdx.x, k = threadIdx.x;
    Wbf[n * 384 + k] = f2bf(Wh[n * 384 + k]);
}

// =====================================================================
// Whole-tree kernel. G=1024 blocks (3 resident/CU by LDS), block b owns
// rows [b*R_j,(b+1)*R_j) at every level, R_j = 1<<j (level 0: 1 row).
// launch_bounds (512,4): VGPR cap 128 — the ONLY safe bound here; (512,6)
// capped at ~85 and triggered wholesale W-remat/spill (r19: VGPR=40,
// FETCH 583MB, 382us). Occupancy comes from grid size, not the bound.
// Levels separated by intra-block vmcnt(0)+barrier; disjoint ws regions.
// Transposed compute, &15 XOR swizzle, counted vmcnt(6) A-DMA pipeline.
// =====================================================================
__global__ __launch_bounds__(512, 4) void k_main(
    const float* __restrict__ c0, const float* __restrict__ c1,
    const float* __restrict__ c2, const float* __restrict__ c3,
    const float* __restrict__ c4, const float* __restrict__ c5,
    const float* __restrict__ c6, const float* __restrict__ c7,
    const float* __restrict__ c8, const float* __restrict__ c9,
    const unsigned short* __restrict__ Wbf,
    const float* __restrict__ Wu, const float* __restrict__ bu,
    const float* __restrict__ bh,
    unsigned short* __restrict__ tbase,
    float* __restrict__ outF)
{
    __shared__ __align__(16) unsigned short A_lds[2][64][128]; // [cc][il][n^swz16]
    __shared__ __align__(16) unsigned short u_lds[64][128];    // [i][n^swz16]
    __shared__ __align__(16) unsigned short wu_lds[8][32][8];

    const int t = threadIdx.x, lane = t & 63, wid = t >> 6;    // 8 waves
    const int l15 = lane & 15, l4 = lane >> 4;
    const int wrow = wid & 3;
    const int wcolh = wid >> 2;
    const int b = blockIdx.x;

    // ---- persistent W fragments: wave's 16-col slice (48 VGPR, pinned) ----
    bf16x8 wreg[12];
    {
        int n = wid * 16 + l15;
        #pragma unroll
        for (int kb = 0; kb < 12; ++kb)
            wreg[kb] = *reinterpret_cast<const bf16x8*>(Wbf + n * 384 + kb * 32 + l4 * 8);
    }
    #pragma unroll
    for (int kb = 0; kb < 12; ++kb)
        asm volatile("" : "+v"(wreg[kb]));

    if (wid == 0 && l4 < 2) {
        #pragma unroll
        for (int nf = 0; nf < 8; ++nf) {
            int n = nf * 16 + l15;
            bf16x8 v = {0, 0, 0, 0, 0, 0, 0, 0};
            if (l4 == 0) {
                #pragma unroll
                for (int k = 0; k < 8; ++k) ((unsigned short*)&v)[k] = f2bf(Wu[n * 8 + k]);
            } else {
                ((unsigned short*)&v)[0] = f2bf(bu[n]);
            }
            *(bf16x8*)&wu_lds[nf][l4 * 16 + l15][0] = v;
        }
    }
    const f32x4 bh4 = *(const f32x4*)&bh[wid * 16 + l4 * 4];

    bf16x8 zeroA = {0, 0, 0, 0, 0, 0, 0, 0};
    bf16x8 onesA = zeroA; ((unsigned short*)&onesA)[0] = 0x3F80;

    __syncthreads();  // wu_lds visible

    // region pointer for level j's emb output (G-independent)
    #define RG(j) (tbase + (size_t)131072 * (512 - (2 << (j))))

    f32x4 cO0 = {0,0,0,0}, cO1 = {0,0,0,0};

    // ================= LEVEL 8 (leaf): T=4 full tiles =================
    {
        const int T = 4;
        const int tb = b * T;
        unsigned short* eOut = RG(8);
        if (l4 == 0) {
            const float* p = c8 + ((size_t)tb * 64 + wrow * 16 + l15) * 8;
            cO0 = *(const f32x4*)p; cO1 = *(const f32x4*)(p + 4);
        }
        for (int tt = 0; tt < T; ++tt) {
            const int tile = tb + tt;
            // ---- u-phase ----
            {
                bf16x8 cb = zeroA;
                if (l4 == 0) {
                    #pragma unroll
                    for (int e = 0; e < 4; ++e) {
                        ((unsigned short*)&cb)[e]     = f2bf(cO0[e]);
                        ((unsigned short*)&cb)[e + 4] = f2bf(cO1[e]);
                    }
                } else if (l4 == 1) cb = onesA;
                const int i = wrow * 16 + l15;
                #pragma unroll
                for (int nfi = 0; nfi < 4; ++nfi) {
                    int nf = wcolh * 4 + nfi;
                    bf16x8 wv = zeroA;
                    if (l4 < 2) wv = *(const bf16x8*)&wu_lds[nf][l4 * 16 + l15][0];
                    f32x4 z = {0.f, 0.f, 0.f, 0.f};
                    z = __builtin_amdgcn_mfma_f32_16x16x32_bf16(wv, cb, z, 0, 0, 0);
                    u16x4 pk;
                    #pragma unroll
                    for (int r = 0; r < 4; ++r) pk[r] = f2bf(fmaxf(z[r], 0.f));
                    int n4 = nf * 16 + l4 * 4;
                    *(u16x4*)&u_lds[i][n4 ^ ((i & 15) << 3)] = pk;
                }
            }
            // ---- child-u: direct loads from c9 ----
            {
                const float* pcBase = c9 + ((size_t)tile * 128 + wrow * 32 + l15) * 8;
                #pragma unroll
                for (int rb = 0; rb < 2; ++rb) {
                    bf16x8 cb = zeroA;
                    if (l4 == 0) {
                        f32x4 a  = *(const f32x4*)(pcBase + rb * 128);
                        f32x4 b2 = *(const f32x4*)(pcBase + rb * 128 + 4);
                        #pragma unroll
                        for (int e = 0; e < 4; ++e) {
                            ((unsigned short*)&cb)[e]     = f2bf(a[e]);
                            ((unsigned short*)&cb)[e + 4] = f2bf(b2[e]);
                        }
                    } else if (l4 == 1) cb = onesA;
                    const int rr = wrow * 32 + rb * 16 + l15;
                    const int cc = rr & 1, il = rr >> 1;
                    #pragma unroll
                    for (int nfi = 0; nfi < 4; ++nfi) {
                        int nf = wcolh * 4 + nfi;
                        bf16x8 wv = zeroA;
                        if (l4 < 2) wv = *(const bf16x8*)&wu_lds[nf][l4 * 16 + l15][0];
                        f32x4 z = {0.f, 0.f, 0.f, 0.f};
                        z = __builtin_amdgcn_mfma_f32_16x16x32_bf16(wv, cb, z, 0, 0, 0);
                        u16x4 pk;
                        #pragma unroll
                        for (int r = 0; r < 4; ++r) pk[r] = f2bf(fmaxf(z[r], 0.f));
                        int n4 = nf * 16 + l4 * 4;
                        *(u16x4*)&A_lds[cc][il][n4 ^ ((il & 15) << 3)] = pk;
                    }
                }
            }
            // ---- prefetch next tile's contents (clamped) ----
            {
                int tn = (tt + 1 < T) ? tile + 1 : tile;
                if (l4 == 0) {
                    const float* p = c8 + ((size_t)tn * 64 + wrow * 16 + l15) * 8;
                    cO0 = *(const f32x4*)p; cO1 = *(const f32x4*)(p + 4);
                }
            }
            asm volatile("s_waitcnt lgkmcnt(0)" ::: "memory");
            __builtin_amdgcn_sched_barrier(0);
            __builtin_amdgcn_s_barrier();
            __builtin_amdgcn_sched_barrier(0);

            f32x4 acc[4];
            #pragma unroll
            for (int mf = 0; mf < 4; ++mf) acc[mf] = bh4;
            #pragma unroll
            for (int kb = 0; kb < 8; ++kb) {
                bf16x8 af[4];
                #pragma unroll
                for (int mf = 0; mf < 4; ++mf) {
                    int i = mf * 16 + l15;
                    af[mf] = *(const bf16x8*)&A_lds[kb >> 2][i][((((kb & 3) * 4) + l4) ^ (i & 15)) * 8];
                }
                #pragma unroll
                for (int mf = 0; mf < 4; ++mf)
                    acc[mf] = __builtin_amdgcn_mfma_f32_16x16x32_bf16(wreg[kb], af[mf], acc[mf], 0, 0, 0);
            }
            #pragma unroll
            for (int kb = 8; kb < 12; ++kb) {
                bf16x8 af[4];
                #pragma unroll
                for (int mf = 0; mf < 4; ++mf) {
                    int i = mf * 16 + l15;
                    af[mf] = *(const bf16x8*)&u_lds[i][((((kb - 8) * 4) + l4) ^ (i & 15)) * 8];
                }
                #pragma unroll
                for (int mf = 0; mf < 4; ++mf)
                    acc[mf] = __builtin_amdgcn_mfma_f32_16x16x32_bf16(wreg[kb], af[mf], acc[mf], 0, 0, 0);
            }
            #pragma unroll
            for (int mf = 0; mf < 4; ++mf) {
                int i = mf * 16 + l15;
                int Rg = tile * 64 + i;
                int rr = Rg & 127, cc = rr & 1, il = rr >> 1;
                u16x4 pk;
                #pragma unroll
                for (int r = 0; r < 4; ++r) pk[r] = f2bf(fmaxf(acc[mf][r], 0.f));
                int n4 = wid * 16 + l4 * 4;
                *(u16x4*)&eOut[(size_t)(Rg >> 7) * 16384 + cc * 8192 + il * 128
                               + (n4 ^ ((il & 15) << 3))] = pk;
            }
            asm volatile("s_waitcnt lgkmcnt(0)" ::: "memory");
            __builtin_amdgcn_sched_barrier(0);
            __builtin_amdgcn_s_barrier();
        }
        asm volatile("s_waitcnt vmcnt(0) lgkmcnt(0)" ::: "memory");
        __builtin_amdgcn_sched_barrier(0);
        __builtin_amdgcn_s_barrier();
    }

    // ================= LEVELS 7..6: full-tile DMA levels =================
    for (int j = 7; j >= 6; --j) {
        const int T = 1 << (j - 6);     // 2, 1
        const int tb = b * T;
        const float* contO = (j == 7) ? c7 : c6;
        const unsigned short* eIn = RG(j + 1);
        unsigned short* eOut = RG(j);

        {
            const unsigned short* src = eIn + (size_t)tb * 16384;
            #pragma unroll
            for (int it = 0; it < 4; ++it) {
                int q = t + it * 512;
                cp16_g2l(src + q * 8, &A_lds[0][0][0] + q * 8);
            }
            if (l4 == 0) {
                const float* p = contO + ((size_t)tb * 64 + wrow * 16 + l15) * 8;
                cO0 = *(const f32x4*)p; cO1 = *(const f32x4*)(p + 4);
            }
        }
        __syncthreads();

        for (int tt = 0; tt < T; ++tt) {
            const int tile = tb + tt;
            {
                bf16x8 cb = zeroA;
                if (l4 == 0) {
                    #pragma unroll
                    for (int e = 0; e < 4; ++e) {
                        ((unsigned short*)&cb)[e]     = f2bf(cO0[e]);
                        ((unsigned short*)&cb)[e + 4] = f2bf(cO1[e]);
                    }
                } else if (l4 == 1) cb = onesA;
                const int i = wrow * 16 + l15;
                #pragma unroll
                for (int nfi = 0; nfi < 4; ++nfi) {
                    int nf = wcolh * 4 + nfi;
                    bf16x8 wv = zeroA;
                    if (l4 < 2) wv = *(const bf16x8*)&wu_lds[nf][l4 * 16 + l15][0];
                    f32x4 z = {0.f, 0.f, 0.f, 0.f};
                    z = __builtin_amdgcn_mfma_f32_16x16x32_bf16(wv, cb, z, 0, 0, 0);
                    u16x4 pk;
                    #pragma unroll
                    for (int r = 0; r < 4; ++r) pk[r] = f2bf(fmaxf(z[r], 0.f));
                    int n4 = nf * 16 + l4 * 4;
                    *(u16x4*)&u_lds[i][n4 ^ ((i & 15) << 3)] = pk;
                }
            }
            {
                int tn = (tt + 1 < T) ? tile + 1 : tile;
                if (l4 == 0) {
                    const float* p = contO + ((size_t)tn * 64 + wrow * 16 + l15) * 8;
                    cO0 = *(const f32x4*)p; cO1 = *(const f32x4*)(p + 4);
                }
            }
            asm volatile("s_waitcnt vmcnt(6)" ::: "memory");  // drain 4 DMA; leave 4 stores + 2 loads
            asm volatile("s_waitcnt lgkmcnt(0)" ::: "memory");
            __builtin_amdgcn_sched_barrier(0);
            __builtin_amdgcn_s_barrier();
            __builtin_amdgcn_sched_barrier(0);

            f32x4 acc[4];
            #pragma unroll
            for (int mf = 0; mf < 4; ++mf) acc[mf] = bh4;
            #pragma unroll
            for (int kb = 0; kb < 8; ++kb) {
                bf16x8 af[4];
                #pragma unroll
                for (int mf = 0; mf < 4; ++mf) {
                    int i = mf * 16 + l15;
                    af[mf] = *(const bf16x8*)&A_lds[kb >> 2][i][((((kb & 3) * 4) + l4) ^ (i & 15)) * 8];
                }
                #pragma unroll
                for (int mf = 0; mf < 4; ++mf)
                    acc[mf] = __builtin_amdgcn_mfma_f32_16x16x32_bf16(wreg[kb], af[mf], acc[mf], 0, 0, 0);
            }
            asm volatile("s_waitcnt lgkmcnt(0)" ::: "memory");
            __builtin_amdgcn_sched_barrier(0);
            __builtin_amdgcn_s_barrier();
            __builtin_amdgcn_sched_barrier(0);
            if (tt + 1 < T) {
                const unsigned short* src = eIn + (size_t)(tile + 1) * 16384;
                #pragma unroll
                for (int it = 0; it < 4; ++it) {
                    int q = t + it * 512;
                    cp16_g2l(src + q * 8, &A_lds[0][0][0] + q * 8);
                }
            }
            #pragma unroll
            for (int kb = 8; kb < 12; ++kb) {
                bf16x8 af[4];
                #pragma unroll
                for (int mf = 0; mf < 4; ++mf) {
                    int i = mf * 16 + l15;
                    af[mf] = *(const bf16x8*)&u_lds[i][((((kb - 8) * 4) + l4) ^ (i & 15)) * 8];
                }
                #pragma unroll
                for (int mf = 0; mf < 4; ++mf)
                    acc[mf] = __builtin_amdgcn_mfma_f32_16x16x32_bf16(wreg[kb], af[mf], acc[mf], 0, 0, 0);
            }
            #pragma unroll
            for (int mf = 0; mf < 4; ++mf) {
                int i = mf * 16 + l15;
                int Rg = tile * 64 + i;
                int rr = Rg & 127, cc = rr & 1, il = rr >> 1;
                u16x4 pk;
                #pragma unroll
                for (int r = 0; r < 4; ++r) pk[r] = f2bf(fmaxf(acc[mf][r], 0.f));
                int n4 = wid * 16 + l4 * 4;
                *(u16x4*)&eOut[(size_t)(Rg >> 7) * 16384 + cc * 8192 + il * 128
                               + (n4 ^ ((il & 15) << 3))] = pk;
            }
            asm volatile("s_waitcnt lgkmcnt(0)" ::: "memory");
            __builtin_amdgcn_sched_barrier(0);
            __builtin_amdgcn_s_barrier();
        }
        asm volatile("s_waitcnt vmcnt(0) lgkmcnt(0)" ::: "memory");
        __builtin_amdgcn_sched_barrier(0);
        __builtin_amdgcn_s_barrier();
    }

    // ================= LEVELS 5..0: partial (reg-staged), R = 1<<j =================
    for (int j = 5; j >= 0; --j) {
        const int R = 1 << j;            // 32..1
        const float* contO = (j == 5) ? c5 : (j == 4) ? c4 : (j == 3) ? c3
                           : (j == 2) ? c2 : (j == 1) ? c1 : c0;
        const unsigned short* eIn = RG(j + 1);
        unsigned short* eOut = (j > 0) ? RG(j) : nullptr;

        const size_t rowBase  = (size_t)b * (size_t)R;
        const size_t crowBase = rowBase * 2;

        {
            const int ilBase = ((int)(crowBase & 127)) >> 1;
            const unsigned short* gb = eIn + (crowBase >> 7) * (size_t)16384
                                     + (size_t)ilBase * 128;
            const int per = R * 16;
            for (int q = t; q < 2 * per; q += 512) {
                int cc = (q >= per) ? 1 : 0;
                int qq = q - cc * per;
                int il = qq >> 4, slot = qq & 15;
                int kc  = slot ^ (il & 15);
                int src = kc ^ ((ilBase + il) & 15);
                bf16x8 v = *(const bf16x8*)(gb + (size_t)cc * 8192 + il * 128 + src * 8);
                *(bf16x8*)&A_lds[cc][il][slot * 8] = v;
            }
        }
        {
            f32x4 a0 = {0,0,0,0}, a1 = {0,0,0,0};
            if (l4 == 0) {
                size_t row = rowBase + (size_t)(wrow * 16 + l15);
                size_t mx = rowBase + R - 1; if (row > mx) row = mx;
                const float* p = contO + row * 8;
                a0 = *(const f32x4*)p; a1 = *(const f32x4*)(p + 4);
            }
            bf16x8 cb = zeroA;
            if (l4 == 0) {
                #pragma unroll
                for (int e = 0; e < 4; ++e) {
                    ((unsigned short*)&cb)[e]     = f2bf(a0[e]);
                    ((unsigned short*)&cb)[e + 4] = f2bf(a1[e]);
                }
            } else if (l4 == 1) cb = onesA;
            const int i = wrow * 16 + l15;
            #pragma unroll
            for (int nfi = 0; nfi < 4; ++nfi) {
                int nf = wcolh * 4 + nfi;
                bf16x8 wv = zeroA;
                if (l4 < 2) wv = *(const bf16x8*)&wu_lds[nf][l4 * 16 + l15][0];
                f32x4 z = {0.f, 0.f, 0.f, 0.f};
                z = __builtin_amdgcn_mfma_f32_16x16x32_bf16(wv, cb, z, 0, 0, 0);
                u16x4 pk;
                #pragma unroll
                for (int r = 0; r < 4; ++r) pk[r] = f2bf(fmaxf(z[r], 0.f));
                int n4 = nf * 16 + l4 * 4;
                *(u16x4*)&u_lds[i][n4 ^ ((i & 15) << 3)] = pk;
            }
        }
        asm volatile("s_waitcnt lgkmcnt(0)" ::: "memory");
        __builtin_amdgcn_sched_barrier(0);
        __builtin_amdgcn_s_barrier();
        __builtin_amdgcn_sched_barrier(0);

        f32x4 acc[4];
        #pragma unroll
        for (int mf = 0; mf < 4; ++mf) acc[mf] = bh4;
        #pragma unroll
        for (int kb = 0; kb < 8; ++kb) {
            bf16x8 af[4];
            #pragma unroll
            for (int mf = 0; mf < 4; ++mf) {
                int i = mf * 16 + l15;
                af[mf] = *(const bf16x8*)&A_lds[kb >> 2][i][((((kb & 3) * 4) + l4) ^ (i & 15)) * 8];
            }
            #pragma unroll
            for (int mf = 0; mf < 4; ++mf)
                acc[mf] = __builtin_amdgcn_mfma_f32_16x16x32_bf16(wreg[kb], af[mf], acc[mf], 0, 0, 0);
        }
        #pragma unroll
        for (int kb = 8; kb < 12; ++kb) {
            bf16x8 af[4];
            #pragma unroll
            for (int mf = 0; mf < 4; ++mf) {
                int i = mf * 16 + l15;
                af[mf] = *(const bf16x8*)&u_lds[i][((((kb - 8) * 4) + l4) ^ (i & 15)) * 8];
            }
            #pragma unroll
            for (int mf = 0; mf < 4; ++mf)
                acc[mf] = __builtin_amdgcn_mfma_f32_16x16x32_bf16(wreg[kb], af[mf], acc[mf], 0, 0, 0);
        }
        if (j == 0) {
            #pragma unroll
            for (int mf = 0; mf < 4; ++mf) {
                int i = mf * 16 + l15;
                if (i < R) {
                    f32x4 o;
                    #pragma unroll
                    for (int r = 0; r < 4; ++r) o[r] = fmaxf(acc[mf][r], 0.f);
                    *(f32x4*)&outF[(rowBase + i) * 128 + wid * 16 + l4 * 4] = o;
                }
            }
        } else {
            #pragma unroll
            for (int mf = 0; mf < 4; ++mf) {
                int i = mf * 16 + l15;
                if (i < R) {
                    size_t Rg = rowBase + i;
                    int rr = (int)(Rg & 127), cc = rr & 1, il = rr >> 1;
                    u16x4 pk;
                    #pragma unroll
                    for (int r = 0; r < 4; ++r) pk[r] = f2bf(fmaxf(acc[mf][r], 0.f));
                    int n4 = wid * 16 + l4 * 4;
                    *(u16x4*)&eOut[(Rg >> 7) * 16384 + cc * 8192 + il * 128
                                   + (n4 ^ ((il & 15) << 3))] = pk;
                }
            }
        }
        asm volatile("s_waitcnt vmcnt(0) lgkmcnt(0)" ::: "memory");
        __builtin_amdgcn_sched_barrier(0);
        __builtin_amdgcn_s_barrier();
    }
    #undef RG
}

extern "C" void kernel_launch(void* const* d_in, const int* in_sizes, int n_in,
                              void* d_out, int out_size, void* d_ws, size_t ws_size,
                              hipStream_t stream) {
    const float* c[10];
    for (int j = 0; j < 10; ++j) c[j] = (const float*)d_in[j];
    const float* Wu = (const float*)d_in[19];
    const float* bu = (const float*)d_in[20];
    const float* Wh = (const float*)d_in[21];
    const float* bh = (const float*)d_in[22];

    unsigned short* Wbf   = (unsigned short*)d_ws;                       // 96 KiB (1 MiB pad)
    unsigned short* tbase = (unsigned short*)((char*)d_ws + (1u << 20)); // per-level regions

    k_cvtW<<<128, 384, 0, stream>>>(Wh, Wbf);
    k_main<<<1024, 512, 0, stream>>>(c[0], c[1], c[2], c[3], c[4], c[5], c[6], c[7],
                                     c[8], c[9], Wbf, Wu, bu, bh, tbase, (float*)d_out);
}

// Round 21
// 125.790 us; speedup vs baseline: 3.0400x; 1.2400x over previous
//
#include <hip/hip_runtime.h>
#include <hip/hip_bf16.h>

typedef __attribute__((ext_vector_type(8))) short bf16x8;
typedef __attribute__((ext_vector_type(4))) float f32x4;
typedef __attribute__((ext_vector_type(4))) unsigned short u16x4;

__device__ __forceinline__ unsigned short f2bf(float f) {
    __hip_bfloat16 h = __float2bfloat16(f);   // RTNE; pairs fuse to v_cvt_pk_bf16_f32
    union { __hip_bfloat16 h; unsigned short u; } v; v.h = h;
    return v.u;
}

__device__ __forceinline__ void cp16_g2l(const void* g, void* l) {
    __builtin_amdgcn_global_load_lds(
        (const __attribute__((address_space(1))) unsigned int*)g,
        (__attribute__((address_space(3))) unsigned int*)l, 16, 0, 0);
}

// ---- one-time: W_h f32 [128][384] -> plain bf16 row-major image in ws ----
__global__ __launch_bounds__(384) void k_cvtW(const float* __restrict__ Wh,
                                              unsigned short* __restrict__ Wbf) {
    int n = blockIdx.x, k = threadIdx.x;
    Wbf[n * 384 + k] = f2bf(Wh[n * 384 + k]);
}

// =====================================================================
// Whole-tree kernel (round-17 configuration — empirical optimum).
// 512 blocks; block b owns rows [b*R_j,(b+1)*R_j) at every level,
// R_j = 2<<j. Children of that slice are the block's OWN previous-level
// output -> no inter-block deps; levels separated by intra-block
// vmcnt(0)+barrier. Each level writes a DISJOINT ws region.
// launch_bounds (512,4): VGPR cap 128 — tighter caps trigger W-remat/spill
// (r19); larger grids halve pipeline depth (r20); LDS fusion of L8->L7
// serializes more than the L3-absorbed traffic it saves (r18).
// Transposed compute (thread owns 4 consecutive cols -> 8B writes),
// full-width &15 XOR swizzle, counted vmcnt(6) A-DMA pipeline.
// =====================================================================
__global__ __launch_bounds__(512, 4) void k_main(
    const float* __restrict__ c0, const float* __restrict__ c1,
    const float* __restrict__ c2, const float* __restrict__ c3,
    const float* __restrict__ c4, const float* __restrict__ c5,
    const float* __restrict__ c6, const float* __restrict__ c7,
    const float* __restrict__ c8, const float* __restrict__ c9,
    const unsigned short* __restrict__ Wbf,
    const float* __restrict__ Wu, const float* __restrict__ bu,
    const float* __restrict__ bh,
    unsigned short* __restrict__ tbase,
    float* __restrict__ outF)
{
    __shared__ __align__(16) unsigned short A_lds[2][64][128]; // [cc][il][n^swz16]
    __shared__ __align__(16) unsigned short u_lds[64][128];    // [i][n^swz16]
    __shared__ __align__(16) unsigned short wu_lds[8][32][8];

    const int t = threadIdx.x, lane = t & 63, wid = t >> 6;    // 8 waves
    const int l15 = lane & 15, l4 = lane >> 4;
    const int wrow = wid & 3;
    const int wcolh = wid >> 2;
    const int b = blockIdx.x;

    // ---- persistent W fragments: wave's 16-col slice (48 VGPR, pinned) ----
    bf16x8 wreg[12];
    {
        int n = wid * 16 + l15;
        #pragma unroll
        for (int kb = 0; kb < 12; ++kb)
            wreg[kb] = *reinterpret_cast<const bf16x8*>(Wbf + n * 384 + kb * 32 + l4 * 8);
    }
    #pragma unroll
    for (int kb = 0; kb < 12; ++kb)
        asm volatile("" : "+v"(wreg[kb]));

    if (wid == 0 && l4 < 2) {
        #pragma unroll
        for (int nf = 0; nf < 8; ++nf) {
            int n = nf * 16 + l15;
            bf16x8 v = {0, 0, 0, 0, 0, 0, 0, 0};
            if (l4 == 0) {
                #pragma unroll
                for (int k = 0; k < 8; ++k) ((unsigned short*)&v)[k] = f2bf(Wu[n * 8 + k]);
            } else {
                ((unsigned short*)&v)[0] = f2bf(bu[n]);
            }
            *(bf16x8*)&wu_lds[nf][l4 * 16 + l15][0] = v;
        }
    }
    const f32x4 bh4 = *(const f32x4*)&bh[wid * 16 + l4 * 4];

    bf16x8 zeroA = {0, 0, 0, 0, 0, 0, 0, 0};
    bf16x8 onesA = zeroA; ((unsigned short*)&onesA)[0] = 0x3F80;

    __syncthreads();  // wu_lds visible

    // region pointer for level j's emb output
    #define RG(j) (tbase + (size_t)131072 * (512 - (2 << (j))))

    f32x4 cO0 = {0,0,0,0}, cO1 = {0,0,0,0};

    // ================= LEVEL 8 (leaf): T=8 full tiles =================
    {
        const int T = 8;
        const int tb = b * T;
        unsigned short* eOut = RG(8);
        if (l4 == 0) {
            const float* p = c8 + ((size_t)tb * 64 + wrow * 16 + l15) * 8;
            cO0 = *(const f32x4*)p; cO1 = *(const f32x4*)(p + 4);
        }
        for (int tt = 0; tt < T; ++tt) {
            const int tile = tb + tt;
            // ---- u-phase ----
            {
                bf16x8 cb = zeroA;
                if (l4 == 0) {
                    #pragma unroll
                    for (int e = 0; e < 4; ++e) {
                        ((unsigned short*)&cb)[e]     = f2bf(cO0[e]);
                        ((unsigned short*)&cb)[e + 4] = f2bf(cO1[e]);
                    }
                } else if (l4 == 1) cb = onesA;
                const int i = wrow * 16 + l15;
                #pragma unroll
                for (int nfi = 0; nfi < 4; ++nfi) {
                    int nf = wcolh * 4 + nfi;
                    bf16x8 wv = zeroA;
                    if (l4 < 2) wv = *(const bf16x8*)&wu_lds[nf][l4 * 16 + l15][0];
                    f32x4 z = {0.f, 0.f, 0.f, 0.f};
                    z = __builtin_amdgcn_mfma_f32_16x16x32_bf16(wv, cb, z, 0, 0, 0);
                    u16x4 pk;
                    #pragma unroll
                    for (int r = 0; r < 4; ++r) pk[r] = f2bf(fmaxf(z[r], 0.f));
                    int n4 = nf * 16 + l4 * 4;
                    *(u16x4*)&u_lds[i][n4 ^ ((i & 15) << 3)] = pk;
                }
            }
            // ---- child-u: direct loads from c9 ----
            {
                const float* pcBase = c9 + ((size_t)tile * 128 + wrow * 32 + l15) * 8;
                #pragma unroll
                for (int rb = 0; rb < 2; ++rb) {
                    bf16x8 cb = zeroA;
                    if (l4 == 0) {
                        f32x4 a  = *(const f32x4*)(pcBase + rb * 128);
                        f32x4 b2 = *(const f32x4*)(pcBase + rb * 128 + 4);
                        #pragma unroll
                        for (int e = 0; e < 4; ++e) {
                            ((unsigned short*)&cb)[e]     = f2bf(a[e]);
                            ((unsigned short*)&cb)[e + 4] = f2bf(b2[e]);
                        }
                    } else if (l4 == 1) cb = onesA;
                    const int rr = wrow * 32 + rb * 16 + l15;
                    const int cc = rr & 1, il = rr >> 1;
                    #pragma unroll
                    for (int nfi = 0; nfi < 4; ++nfi) {
                        int nf = wcolh * 4 + nfi;
                        bf16x8 wv = zeroA;
                        if (l4 < 2) wv = *(const bf16x8*)&wu_lds[nf][l4 * 16 + l15][0];
                        f32x4 z = {0.f, 0.f, 0.f, 0.f};
                        z = __builtin_amdgcn_mfma_f32_16x16x32_bf16(wv, cb, z, 0, 0, 0);
                        u16x4 pk;
                        #pragma unroll
                        for (int r = 0; r < 4; ++r) pk[r] = f2bf(fmaxf(z[r], 0.f));
                        int n4 = nf * 16 + l4 * 4;
                        *(u16x4*)&A_lds[cc][il][n4 ^ ((il & 15) << 3)] = pk;
                    }
                }
            }
            // ---- prefetch next tile's contents (clamped) ----
            {
                int tn = (tt + 1 < T) ? tile + 1 : tile;
                if (l4 == 0) {
                    const float* p = c8 + ((size_t)tn * 64 + wrow * 16 + l15) * 8;
                    cO0 = *(const f32x4*)p; cO1 = *(const f32x4*)(p + 4);
                }
            }
            asm volatile("s_waitcnt lgkmcnt(0)" ::: "memory");
            __builtin_amdgcn_sched_barrier(0);
            __builtin_amdgcn_s_barrier();
            __builtin_amdgcn_sched_barrier(0);

            f32x4 acc[4];
            #pragma unroll
            for (int mf = 0; mf < 4; ++mf) acc[mf] = bh4;
            #pragma unroll
            for (int kb = 0; kb < 8; ++kb) {
                bf16x8 af[4];
                #pragma unroll
                for (int mf = 0; mf < 4; ++mf) {
                    int i = mf * 16 + l15;
                    af[mf] = *(const bf16x8*)&A_lds[kb >> 2][i][((((kb & 3) * 4) + l4) ^ (i & 15)) * 8];
                }
                #pragma unroll
                for (int mf = 0; mf < 4; ++mf)
                    acc[mf] = __builtin_amdgcn_mfma_f32_16x16x32_bf16(wreg[kb], af[mf], acc[mf], 0, 0, 0);
            }
            #pragma unroll
            for (int kb = 8; kb < 12; ++kb) {
                bf16x8 af[4];
                #pragma unroll
                for (int mf = 0; mf < 4; ++mf) {
                    int i = mf * 16 + l15;
                    af[mf] = *(const bf16x8*)&u_lds[i][((((kb - 8) * 4) + l4) ^ (i & 15)) * 8];
                }
                #pragma unroll
                for (int mf = 0; mf < 4; ++mf)
                    acc[mf] = __builtin_amdgcn_mfma_f32_16x16x32_bf16(wreg[kb], af[mf], acc[mf], 0, 0, 0);
            }
            #pragma unroll
            for (int mf = 0; mf < 4; ++mf) {
                int i = mf * 16 + l15;
                int Rg = tile * 64 + i;
                int rr = Rg & 127, cc = rr & 1, il = rr >> 1;
                u16x4 pk;
                #pragma unroll
                for (int r = 0; r < 4; ++r) pk[r] = f2bf(fmaxf(acc[mf][r], 0.f));
                int n4 = wid * 16 + l4 * 4;
                *(u16x4*)&eOut[(size_t)(Rg >> 7) * 16384 + cc * 8192 + il * 128
                               + (n4 ^ ((il & 15) << 3))] = pk;
            }
            asm volatile("s_waitcnt lgkmcnt(0)" ::: "memory");
            __builtin_amdgcn_sched_barrier(0);
            __builtin_amdgcn_s_barrier();
        }
        asm volatile("s_waitcnt vmcnt(0) lgkmcnt(0)" ::: "memory");
        __builtin_amdgcn_sched_barrier(0);
        __builtin_amdgcn_s_barrier();
    }

    // ================= LEVELS 7..5: full-tile DMA levels =================
    for (int j = 7; j >= 5; --j) {
        const int T = 1 << (j - 5);     // 4, 2, 1
        const int tb = b * T;
        const float* contO = (j == 7) ? c7 : (j == 6) ? c6 : c5;
        const unsigned short* eIn = RG(j + 1);
        unsigned short* eOut = RG(j);

        {
            const unsigned short* src = eIn + (size_t)tb * 16384;
            #pragma unroll
            for (int it = 0; it < 4; ++it) {
                int q = t + it * 512;
                cp16_g2l(src + q * 8, &A_lds[0][0][0] + q * 8);
            }
            if (l4 == 0) {
                const float* p = contO + ((size_t)tb * 64 + wrow * 16 + l15) * 8;
                cO0 = *(const f32x4*)p; cO1 = *(const f32x4*)(p + 4);
            }
        }
        __syncthreads();

        for (int tt = 0; tt < T; ++tt) {
            const int tile = tb + tt;
            {
                bf16x8 cb = zeroA;
                if (l4 == 0) {
                    #pragma unroll
                    for (int e = 0; e < 4; ++e) {
                        ((unsigned short*)&cb)[e]     = f2bf(cO0[e]);
                        ((unsigned short*)&cb)[e + 4] = f2bf(cO1[e]);
                    }
                } else if (l4 == 1) cb = onesA;
                const int i = wrow * 16 + l15;
                #pragma unroll
                for (int nfi = 0; nfi < 4; ++nfi) {
                    int nf = wcolh * 4 + nfi;
                    bf16x8 wv = zeroA;
                    if (l4 < 2) wv = *(const bf16x8*)&wu_lds[nf][l4 * 16 + l15][0];
                    f32x4 z = {0.f, 0.f, 0.f, 0.f};
                    z = __builtin_amdgcn_mfma_f32_16x16x32_bf16(wv, cb, z, 0, 0, 0);
                    u16x4 pk;
                    #pragma unroll
                    for (int r = 0; r < 4; ++r) pk[r] = f2bf(fmaxf(z[r], 0.f));
                    int n4 = nf * 16 + l4 * 4;
                    *(u16x4*)&u_lds[i][n4 ^ ((i & 15) << 3)] = pk;
                }
            }
            {
                int tn = (tt + 1 < T) ? tile + 1 : tile;
                if (l4 == 0) {
                    const float* p = contO + ((size_t)tn * 64 + wrow * 16 + l15) * 8;
                    cO0 = *(const f32x4*)p; cO1 = *(const f32x4*)(p + 4);
                }
            }
            asm volatile("s_waitcnt vmcnt(6)" ::: "memory");  // drain 4 DMA; leave 4 stores + 2 loads
            asm volatile("s_waitcnt lgkmcnt(0)" ::: "memory");
            __builtin_amdgcn_sched_barrier(0);
            __builtin_amdgcn_s_barrier();
            __builtin_amdgcn_sched_barrier(0);

            f32x4 acc[4];
            #pragma unroll
            for (int mf = 0; mf < 4; ++mf) acc[mf] = bh4;
            #pragma unroll
            for (int kb = 0; kb < 8; ++kb) {
                bf16x8 af[4];
                #pragma unroll
                for (int mf = 0; mf < 4; ++mf) {
                    int i = mf * 16 + l15;
                    af[mf] = *(const bf16x8*)&A_lds[kb >> 2][i][((((kb & 3) * 4) + l4) ^ (i & 15)) * 8];
                }
                #pragma unroll
                for (int mf = 0; mf < 4; ++mf)
                    acc[mf] = __builtin_amdgcn_mfma_f32_16x16x32_bf16(wreg[kb], af[mf], acc[mf], 0, 0, 0);
            }
            asm volatile("s_waitcnt lgkmcnt(0)" ::: "memory");
            __builtin_amdgcn_sched_barrier(0);
            __builtin_amdgcn_s_barrier();
            __builtin_amdgcn_sched_barrier(0);
            if (tt + 1 < T) {
                const unsigned short* src = eIn + (size_t)(tile + 1) * 16384;
                #pragma unroll
                for (int it = 0; it < 4; ++it) {
                    int q = t + it * 512;
                    cp16_g2l(src + q * 8, &A_lds[0][0][0] + q * 8);
                }
            }
            #pragma unroll
            for (int kb = 8; kb < 12; ++kb) {
                bf16x8 af[4];
                #pragma unroll
                for (int mf = 0; mf < 4; ++mf) {
                    int i = mf * 16 + l15;
                    af[mf] = *(const bf16x8*)&u_lds[i][((((kb - 8) * 4) + l4) ^ (i & 15)) * 8];
                }
                #pragma unroll
                for (int mf = 0; mf < 4; ++mf)
                    acc[mf] = __builtin_amdgcn_mfma_f32_16x16x32_bf16(wreg[kb], af[mf], acc[mf], 0, 0, 0);
            }
            #pragma unroll
            for (int mf = 0; mf < 4; ++mf) {
                int i = mf * 16 + l15;
                int Rg = tile * 64 + i;
                int rr = Rg & 127, cc = rr & 1, il = rr >> 1;
                u16x4 pk;
                #pragma unroll
                for (int r = 0; r < 4; ++r) pk[r] = f2bf(fmaxf(acc[mf][r], 0.f));
                int n4 = wid * 16 + l4 * 4;
                *(u16x4*)&eOut[(size_t)(Rg >> 7) * 16384 + cc * 8192 + il * 128
                               + (n4 ^ ((il & 15) << 3))] = pk;
            }
            asm volatile("s_waitcnt lgkmcnt(0)" ::: "memory");
            __builtin_amdgcn_sched_barrier(0);
            __builtin_amdgcn_s_barrier();
        }
        asm volatile("s_waitcnt vmcnt(0) lgkmcnt(0)" ::: "memory");
        __builtin_amdgcn_sched_barrier(0);
        __builtin_amdgcn_s_barrier();
    }

    // ================= LEVELS 4..0: partial (reg-staged) =================
    for (int j = 4; j >= 0; --j) {
        const int R = 2 << j;            // 32..2
        const float* contO = (j == 4) ? c4 : (j == 3) ? c3 : (j == 2) ? c2
                           : (j == 1) ? c1 : c0;
        const unsigned short* eIn = RG(j + 1);
        unsigned short* eOut = (j > 0) ? RG(j) : nullptr;

        const size_t rowBase  = (size_t)b * (size_t)R;
        const size_t crowBase = rowBase * 2;

        {
            const int ilBase = ((int)(crowBase & 127)) >> 1;
            const unsigned short* gb = eIn + (crowBase >> 7) * (size_t)16384
                                     + (size_t)ilBase * 128;
            const int per = R * 16;
            for (int q = t; q < 2 * per; q += 512) {
                int cc = (q >= per) ? 1 : 0;
                int qq = q - cc * per;
                int il = qq >> 4, slot = qq & 15;
                int kc  = slot ^ (il & 15);
                int src = kc ^ ((ilBase + il) & 15);
                bf16x8 v = *(const bf16x8*)(gb + (size_t)cc * 8192 + il * 128 + src * 8);
                *(bf16x8*)&A_lds[cc][il][slot * 8] = v;
            }
        }
        {
            f32x4 a0 = {0,0,0,0}, a1 = {0,0,0,0};
            if (l4 == 0) {
                size_t row = rowBase + (size_t)(wrow * 16 + l15);
                size_t mx = rowBase + R - 1; if (row > mx) row = mx;
                const float* p = contO + row * 8;
                a0 = *(const f32x4*)p; a1 = *(const f32x4*)(p + 4);
            }
            bf16x8 cb = zeroA;
            if (l4 == 0) {
                #pragma unroll
                for (int e = 0; e < 4; ++e) {
                    ((unsigned short*)&cb)[e]     = f2bf(a0[e]);
                    ((unsigned short*)&cb)[e + 4] = f2bf(a1[e]);
                }
            } else if (l4 == 1) cb = onesA;
            const int i = wrow * 16 + l15;
            #pragma unroll
            for (int nfi = 0; nfi < 4; ++nfi) {
                int nf = wcolh * 4 + nfi;
                bf16x8 wv = zeroA;
                if (l4 < 2) wv = *(const bf16x8*)&wu_lds[nf][l4 * 16 + l15][0];
                f32x4 z = {0.f, 0.f, 0.f, 0.f};
                z = __builtin_amdgcn_mfma_f32_16x16x32_bf16(wv, cb, z, 0, 0, 0);
                u16x4 pk;
                #pragma unroll
                for (int r = 0; r < 4; ++r) pk[r] = f2bf(fmaxf(z[r], 0.f));
                int n4 = nf * 16 + l4 * 4;
                *(u16x4*)&u_lds[i][n4 ^ ((i & 15) << 3)] = pk;
            }
        }
        asm volatile("s_waitcnt lgkmcnt(0)" ::: "memory");
        __builtin_amdgcn_sched_barrier(0);
        __builtin_amdgcn_s_barrier();
        __builtin_amdgcn_sched_barrier(0);

        f32x4 acc[4];
        #pragma unroll
        for (int mf = 0; mf < 4; ++mf) acc[mf] = bh4;
        #pragma unroll
        for (int kb = 0; kb < 8; ++kb) {
            bf16x8 af[4];
            #pragma unroll
            for (int mf = 0; mf < 4; ++mf) {
                int i = mf * 16 + l15;
                af[mf] = *(const bf16x8*)&A_lds[kb >> 2][i][((((kb & 3) * 4) + l4) ^ (i & 15)) * 8];
            }
            #pragma unroll
            for (int mf = 0; mf < 4; ++mf)
                acc[mf] = __builtin_amdgcn_mfma_f32_16x16x32_bf16(wreg[kb], af[mf], acc[mf], 0, 0, 0);
        }
        #pragma unroll
        for (int kb = 8; kb < 12; ++kb) {
            bf16x8 af[4];
            #pragma unroll
            for (int mf = 0; mf < 4; ++mf) {
                int i = mf * 16 + l15;
                af[mf] = *(const bf16x8*)&u_lds[i][((((kb - 8) * 4) + l4) ^ (i & 15)) * 8];
            }
            #pragma unroll
            for (int mf = 0; mf < 4; ++mf)
                acc[mf] = __builtin_amdgcn_mfma_f32_16x16x32_bf16(wreg[kb], af[mf], acc[mf], 0, 0, 0);
        }
        if (j == 0) {
            #pragma unroll
            for (int mf = 0; mf < 4; ++mf) {
                int i = mf * 16 + l15;
                if (i < R) {
                    f32x4 o;
                    #pragma unroll
                    for (int r = 0; r < 4; ++r) o[r] = fmaxf(acc[mf][r], 0.f);
                    *(f32x4*)&outF[(rowBase + i) * 128 + wid * 16 + l4 * 4] = o;
                }
            }
        } else {
            #pragma unroll
            for (int mf = 0; mf < 4; ++mf) {
                int i = mf * 16 + l15;
                if (i < R) {
                    size_t Rg = rowBase + i;
                    int rr = (int)(Rg & 127), cc = rr & 1, il = rr >> 1;
                    u16x4 pk;
                    #pragma unroll
                    for (int r = 0; r < 4; ++r) pk[r] = f2bf(fmaxf(acc[mf][r], 0.f));
                    int n4 = wid * 16 + l4 * 4;
                    *(u16x4*)&eOut[(Rg >> 7) * 16384 + cc * 8192 + il * 128
                                   + (n4 ^ ((il & 15) << 3))] = pk;
                }
            }
        }
        asm volatile("s_waitcnt vmcnt(0) lgkmcnt(0)" ::: "memory");
        __builtin_amdgcn_sched_barrier(0);
        __builtin_amdgcn_s_barrier();
    }
    #undef RG
}

extern "C" void kernel_launch(void* const* d_in, const int* in_sizes, int n_in,
                              void* d_out, int out_size, void* d_ws, size_t ws_size,
                              hipStream_t stream) {
    const float* c[10];
    for (int j = 0; j < 10; ++j) c[j] = (const float*)d_in[j];
    const float* Wu = (const float*)d_in[19];
    const float* bu = (const float*)d_in[20];
    const float* Wh = (const float*)d_in[21];
    const float* bh = (const float*)d_in[22];

    unsigned short* Wbf   = (unsigned short*)d_ws;                       // 96 KiB (1 MiB pad)
    unsigned short* tbase = (unsigned short*)((char*)d_ws + (1u << 20)); // per-level regions

    k_cvtW<<<128, 384, 0, stream>>>(Wh, Wbf);
    k_main<<<512, 512, 0, stream>>>(c[0], c[1], c[2], c[3], c[4], c[5], c[6], c[7],
                                    c[8], c[9], Wbf, Wu, bu, bh, tbase, (float*)d_out);
}

// Round 22
// 115.533 us; speedup vs baseline: 3.3099x; 1.0888x over previous
//
#include <hip/hip_runtime.h>
#include <hip/hip_bf16.h>

typedef __attribute__((ext_vector_type(8))) short bf16x8;
typedef __attribute__((ext_vector_type(4))) float f32x4;
typedef __attribute__((ext_vector_type(4))) unsigned short u16x4;

__device__ __forceinline__ unsigned short f2bf(float f) {
    __hip_bfloat16 h = __float2bfloat16(f);   // RTNE; pairs fuse to v_cvt_pk_bf16_f32
    union { __hip_bfloat16 h; unsigned short u; } v; v.h = h;
    return v.u;
}

__device__ __forceinline__ void cp16_g2l(const void* g, void* l) {
    __builtin_amdgcn_global_load_lds(
        (const __attribute__((address_space(1))) unsigned int*)g,
        (__attribute__((address_space(3))) unsigned int*)l, 16, 0, 0);
}

// ---- one-time: W_h f32 [128][384] -> plain bf16 row-major image in ws ----
__global__ __launch_bounds__(384) void k_cvtW(const float* __restrict__ Wh,
                                              unsigned short* __restrict__ Wbf) {
    int n = blockIdx.x, k = threadIdx.x;
    Wbf[n * 384 + k] = f2bf(Wh[n * 384 + k]);
}

// =====================================================================
// Whole-tree kernel (round-17 configuration + T5 setprio on GEMM clusters).
// 512 blocks; block b owns rows [b*R_j,(b+1)*R_j) at every level,
// R_j = 2<<j. Children of that slice are the block's OWN previous-level
// output -> no inter-block deps; levels separated by intra-block
// vmcnt(0)+barrier. Each level writes a DISJOINT ws region.
// launch_bounds (512,4): VGPR cap 128 — tighter caps trigger W-remat/spill
// (r19); larger grids halve pipeline depth (r20); LDS fusion of L8->L7
// serializes more than the L3-absorbed traffic it saves (r18).
// setprio(1) wraps the main-GEMM ds_read+MFMA clusters: with 2 resident
// blocks/CU at different phases, the CU scheduler prefers the GEMM-phase
// block over the staging block (T5 cross-block arbitration regime).
// Transposed compute (thread owns 4 consecutive cols -> 8B writes),
// full-width &15 XOR swizzle, counted vmcnt(6) A-DMA pipeline.
// =====================================================================
__global__ __launch_bounds__(512, 4) void k_main(
    const float* __restrict__ c0, const float* __restrict__ c1,
    const float* __restrict__ c2, const float* __restrict__ c3,
    const float* __restrict__ c4, const float* __restrict__ c5,
    const float* __restrict__ c6, const float* __restrict__ c7,
    const float* __restrict__ c8, const float* __restrict__ c9,
    const unsigned short* __restrict__ Wbf,
    const float* __restrict__ Wu, const float* __restrict__ bu,
    const float* __restrict__ bh,
    unsigned short* __restrict__ tbase,
    float* __restrict__ outF)
{
    __shared__ __align__(16) unsigned short A_lds[2][64][128]; // [cc][il][n^swz16]
    __shared__ __align__(16) unsigned short u_lds[64][128];    // [i][n^swz16]
    __shared__ __align__(16) unsigned short wu_lds[8][32][8];

    const int t = threadIdx.x, lane = t & 63, wid = t >> 6;    // 8 waves
    const int l15 = lane & 15, l4 = lane >> 4;
    const int wrow = wid & 3;
    const int wcolh = wid >> 2;
    const int b = blockIdx.x;

    // ---- persistent W fragments: wave's 16-col slice (48 VGPR, pinned) ----
    bf16x8 wreg[12];
    {
        int n = wid * 16 + l15;
        #pragma unroll
        for (int kb = 0; kb < 12; ++kb)
            wreg[kb] = *reinterpret_cast<const bf16x8*>(Wbf + n * 384 + kb * 32 + l4 * 8);
    }
    #pragma unroll
    for (int kb = 0; kb < 12; ++kb)
        asm volatile("" : "+v"(wreg[kb]));

    if (wid == 0 && l4 < 2) {
        #pragma unroll
        for (int nf = 0; nf < 8; ++nf) {
            int n = nf * 16 + l15;
            bf16x8 v = {0, 0, 0, 0, 0, 0, 0, 0};
            if (l4 == 0) {
                #pragma unroll
                for (int k = 0; k < 8; ++k) ((unsigned short*)&v)[k] = f2bf(Wu[n * 8 + k]);
            } else {
                ((unsigned short*)&v)[0] = f2bf(bu[n]);
            }
            *(bf16x8*)&wu_lds[nf][l4 * 16 + l15][0] = v;
        }
    }
    const f32x4 bh4 = *(const f32x4*)&bh[wid * 16 + l4 * 4];

    bf16x8 zeroA = {0, 0, 0, 0, 0, 0, 0, 0};
    bf16x8 onesA = zeroA; ((unsigned short*)&onesA)[0] = 0x3F80;

    __syncthreads();  // wu_lds visible

    // region pointer for level j's emb output
    #define RG(j) (tbase + (size_t)131072 * (512 - (2 << (j))))

    f32x4 cO0 = {0,0,0,0}, cO1 = {0,0,0,0};

    // ================= LEVEL 8 (leaf): T=8 full tiles =================
    {
        const int T = 8;
        const int tb = b * T;
        unsigned short* eOut = RG(8);
        if (l4 == 0) {
            const float* p = c8 + ((size_t)tb * 64 + wrow * 16 + l15) * 8;
            cO0 = *(const f32x4*)p; cO1 = *(const f32x4*)(p + 4);
        }
        for (int tt = 0; tt < T; ++tt) {
            const int tile = tb + tt;
            // ---- u-phase ----
            {
                bf16x8 cb = zeroA;
                if (l4 == 0) {
                    #pragma unroll
                    for (int e = 0; e < 4; ++e) {
                        ((unsigned short*)&cb)[e]     = f2bf(cO0[e]);
                        ((unsigned short*)&cb)[e + 4] = f2bf(cO1[e]);
                    }
                } else if (l4 == 1) cb = onesA;
                const int i = wrow * 16 + l15;
                #pragma unroll
                for (int nfi = 0; nfi < 4; ++nfi) {
                    int nf = wcolh * 4 + nfi;
                    bf16x8 wv = zeroA;
                    if (l4 < 2) wv = *(const bf16x8*)&wu_lds[nf][l4 * 16 + l15][0];
                    f32x4 z = {0.f, 0.f, 0.f, 0.f};
                    z = __builtin_amdgcn_mfma_f32_16x16x32_bf16(wv, cb, z, 0, 0, 0);
                    u16x4 pk;
                    #pragma unroll
                    for (int r = 0; r < 4; ++r) pk[r] = f2bf(fmaxf(z[r], 0.f));
                    int n4 = nf * 16 + l4 * 4;
                    *(u16x4*)&u_lds[i][n4 ^ ((i & 15) << 3)] = pk;
                }
            }
            // ---- child-u: direct loads from c9 ----
            {
                const float* pcBase = c9 + ((size_t)tile * 128 + wrow * 32 + l15) * 8;
                #pragma unroll
                for (int rb = 0; rb < 2; ++rb) {
                    bf16x8 cb = zeroA;
                    if (l4 == 0) {
                        f32x4 a  = *(const f32x4*)(pcBase + rb * 128);
                        f32x4 b2 = *(const f32x4*)(pcBase + rb * 128 + 4);
                        #pragma unroll
                        for (int e = 0; e < 4; ++e) {
                            ((unsigned short*)&cb)[e]     = f2bf(a[e]);
                            ((unsigned short*)&cb)[e + 4] = f2bf(b2[e]);
                        }
                    } else if (l4 == 1) cb = onesA;
                    const int rr = wrow * 32 + rb * 16 + l15;
                    const int cc = rr & 1, il = rr >> 1;
                    #pragma unroll
                    for (int nfi = 0; nfi < 4; ++nfi) {
                        int nf = wcolh * 4 + nfi;
                        bf16x8 wv = zeroA;
                        if (l4 < 2) wv = *(const bf16x8*)&wu_lds[nf][l4 * 16 + l15][0];
                        f32x4 z = {0.f, 0.f, 0.f, 0.f};
                        z = __builtin_amdgcn_mfma_f32_16x16x32_bf16(wv, cb, z, 0, 0, 0);
                        u16x4 pk;
                        #pragma unroll
                        for (int r = 0; r < 4; ++r) pk[r] = f2bf(fmaxf(z[r], 0.f));
                        int n4 = nf * 16 + l4 * 4;
                        *(u16x4*)&A_lds[cc][il][n4 ^ ((il & 15) << 3)] = pk;
                    }
                }
            }
            // ---- prefetch next tile's contents (clamped) ----
            {
                int tn = (tt + 1 < T) ? tile + 1 : tile;
                if (l4 == 0) {
                    const float* p = c8 + ((size_t)tn * 64 + wrow * 16 + l15) * 8;
                    cO0 = *(const f32x4*)p; cO1 = *(const f32x4*)(p + 4);
                }
            }
            asm volatile("s_waitcnt lgkmcnt(0)" ::: "memory");
            __builtin_amdgcn_sched_barrier(0);
            __builtin_amdgcn_s_barrier();
            __builtin_amdgcn_sched_barrier(0);

            f32x4 acc[4];
            #pragma unroll
            for (int mf = 0; mf < 4; ++mf) acc[mf] = bh4;
            __builtin_amdgcn_s_setprio(1);
            #pragma unroll
            for (int kb = 0; kb < 8; ++kb) {
                bf16x8 af[4];
                #pragma unroll
                for (int mf = 0; mf < 4; ++mf) {
                    int i = mf * 16 + l15;
                    af[mf] = *(const bf16x8*)&A_lds[kb >> 2][i][((((kb & 3) * 4) + l4) ^ (i & 15)) * 8];
                }
                #pragma unroll
                for (int mf = 0; mf < 4; ++mf)
                    acc[mf] = __builtin_amdgcn_mfma_f32_16x16x32_bf16(wreg[kb], af[mf], acc[mf], 0, 0, 0);
            }
            #pragma unroll
            for (int kb = 8; kb < 12; ++kb) {
                bf16x8 af[4];
                #pragma unroll
                for (int mf = 0; mf < 4; ++mf) {
                    int i = mf * 16 + l15;
                    af[mf] = *(const bf16x8*)&u_lds[i][((((kb - 8) * 4) + l4) ^ (i & 15)) * 8];
                }
                #pragma unroll
                for (int mf = 0; mf < 4; ++mf)
                    acc[mf] = __builtin_amdgcn_mfma_f32_16x16x32_bf16(wreg[kb], af[mf], acc[mf], 0, 0, 0);
            }
            __builtin_amdgcn_s_setprio(0);
            #pragma unroll
            for (int mf = 0; mf < 4; ++mf) {
                int i = mf * 16 + l15;
                int Rg = tile * 64 + i;
                int rr = Rg & 127, cc = rr & 1, il = rr >> 1;
                u16x4 pk;
                #pragma unroll
                for (int r = 0; r < 4; ++r) pk[r] = f2bf(fmaxf(acc[mf][r], 0.f));
                int n4 = wid * 16 + l4 * 4;
                *(u16x4*)&eOut[(size_t)(Rg >> 7) * 16384 + cc * 8192 + il * 128
                               + (n4 ^ ((il & 15) << 3))] = pk;
            }
            asm volatile("s_waitcnt lgkmcnt(0)" ::: "memory");
            __builtin_amdgcn_sched_barrier(0);
            __builtin_amdgcn_s_barrier();
        }
        asm volatile("s_waitcnt vmcnt(0) lgkmcnt(0)" ::: "memory");
        __builtin_amdgcn_sched_barrier(0);
        __builtin_amdgcn_s_barrier();
    }

    // ================= LEVELS 7..5: full-tile DMA levels =================
    for (int j = 7; j >= 5; --j) {
        const int T = 1 << (j - 5);     // 4, 2, 1
        const int tb = b * T;
        const float* contO = (j == 7) ? c7 : (j == 6) ? c6 : c5;
        const unsigned short* eIn = RG(j + 1);
        unsigned short* eOut = RG(j);

        {
            const unsigned short* src = eIn + (size_t)tb * 16384;
            #pragma unroll
            for (int it = 0; it < 4; ++it) {
                int q = t + it * 512;
                cp16_g2l(src + q * 8, &A_lds[0][0][0] + q * 8);
            }
            if (l4 == 0) {
                const float* p = contO + ((size_t)tb * 64 + wrow * 16 + l15) * 8;
                cO0 = *(const f32x4*)p; cO1 = *(const f32x4*)(p + 4);
            }
        }
        __syncthreads();

        for (int tt = 0; tt < T; ++tt) {
            const int tile = tb + tt;
            {
                bf16x8 cb = zeroA;
                if (l4 == 0) {
                    #pragma unroll
                    for (int e = 0; e < 4; ++e) {
                        ((unsigned short*)&cb)[e]     = f2bf(cO0[e]);
                        ((unsigned short*)&cb)[e + 4] = f2bf(cO1[e]);
                    }
                } else if (l4 == 1) cb = onesA;
                const int i = wrow * 16 + l15;
                #pragma unroll
                for (int nfi = 0; nfi < 4; ++nfi) {
                    int nf = wcolh * 4 + nfi;
                    bf16x8 wv = zeroA;
                    if (l4 < 2) wv = *(const bf16x8*)&wu_lds[nf][l4 * 16 + l15][0];
                    f32x4 z = {0.f, 0.f, 0.f, 0.f};
                    z = __builtin_amdgcn_mfma_f32_16x16x32_bf16(wv, cb, z, 0, 0, 0);
                    u16x4 pk;
                    #pragma unroll
                    for (int r = 0; r < 4; ++r) pk[r] = f2bf(fmaxf(z[r], 0.f));
                    int n4 = nf * 16 + l4 * 4;
                    *(u16x4*)&u_lds[i][n4 ^ ((i & 15) << 3)] = pk;
                }
            }
            {
                int tn = (tt + 1 < T) ? tile + 1 : tile;
                if (l4 == 0) {
                    const float* p = contO + ((size_t)tn * 64 + wrow * 16 + l15) * 8;
                    cO0 = *(const f32x4*)p; cO1 = *(const f32x4*)(p + 4);
                }
            }
            asm volatile("s_waitcnt vmcnt(6)" ::: "memory");  // drain 4 DMA; leave 4 stores + 2 loads
            asm volatile("s_waitcnt lgkmcnt(0)" ::: "memory");
            __builtin_amdgcn_sched_barrier(0);
            __builtin_amdgcn_s_barrier();
            __builtin_amdgcn_sched_barrier(0);

            f32x4 acc[4];
            #pragma unroll
            for (int mf = 0; mf < 4; ++mf) acc[mf] = bh4;
            __builtin_amdgcn_s_setprio(1);
            #pragma unroll
            for (int kb = 0; kb < 8; ++kb) {
                bf16x8 af[4];
                #pragma unroll
                for (int mf = 0; mf < 4; ++mf) {
                    int i = mf * 16 + l15;
                    af[mf] = *(const bf16x8*)&A_lds[kb >> 2][i][((((kb & 3) * 4) + l4) ^ (i & 15)) * 8];
                }
                #pragma unroll
                for (int mf = 0; mf < 4; ++mf)
                    acc[mf] = __builtin_amdgcn_mfma_f32_16x16x32_bf16(wreg[kb], af[mf], acc[mf], 0, 0, 0);
            }
            __builtin_amdgcn_s_setprio(0);
            asm volatile("s_waitcnt lgkmcnt(0)" ::: "memory");
            __builtin_amdgcn_sched_barrier(0);
            __builtin_amdgcn_s_barrier();
            __builtin_amdgcn_sched_barrier(0);
            if (tt + 1 < T) {
                const unsigned short* src = eIn + (size_t)(tile + 1) * 16384;
                #pragma unroll
                for (int it = 0; it < 4; ++it) {
                    int q = t + it * 512;
                    cp16_g2l(src + q * 8, &A_lds[0][0][0] + q * 8);
                }
            }
            __builtin_amdgcn_s_setprio(1);
            #pragma unroll
            for (int kb = 8; kb < 12; ++kb) {
                bf16x8 af[4];
                #pragma unroll
                for (int mf = 0; mf < 4; ++mf) {
                    int i = mf * 16 + l15;
                    af[mf] = *(const bf16x8*)&u_lds[i][((((kb - 8) * 4) + l4) ^ (i & 15)) * 8];
                }
                #pragma unroll
                for (int mf = 0; mf < 4; ++mf)
                    acc[mf] = __builtin_amdgcn_mfma_f32_16x16x32_bf16(wreg[kb], af[mf], acc[mf], 0, 0, 0);
            }
            __builtin_amdgcn_s_setprio(0);
            #pragma unroll
            for (int mf = 0; mf < 4; ++mf) {
                int i = mf * 16 + l15;
                int Rg = tile * 64 + i;
                int rr = Rg & 127, cc = rr & 1, il = rr >> 1;
                u16x4 pk;
                #pragma unroll
                for (int r = 0; r < 4; ++r) pk[r] = f2bf(fmaxf(acc[mf][r], 0.f));
                int n4 = wid * 16 + l4 * 4;
                *(u16x4*)&eOut[(size_t)(Rg >> 7) * 16384 + cc * 8192 + il * 128
                               + (n4 ^ ((il & 15) << 3))] = pk;
            }
            asm volatile("s_waitcnt lgkmcnt(0)" ::: "memory");
            __builtin_amdgcn_sched_barrier(0);
            __builtin_amdgcn_s_barrier();
        }
        asm volatile("s_waitcnt vmcnt(0) lgkmcnt(0)" ::: "memory");
        __builtin_amdgcn_sched_barrier(0);
        __builtin_amdgcn_s_barrier();
    }

    // ================= LEVELS 4..0: partial (reg-staged) =================
    for (int j = 4; j >= 0; --j) {
        const int R = 2 << j;            // 32..2
        const float* contO = (j == 4) ? c4 : (j == 3) ? c3 : (j == 2) ? c2
                           : (j == 1) ? c1 : c0;
        const unsigned short* eIn = RG(j + 1);
        unsigned short* eOut = (j > 0) ? RG(j) : nullptr;

        const size_t rowBase  = (size_t)b * (size_t)R;
        const size_t crowBase = rowBase * 2;

        {
            const int ilBase = ((int)(crowBase & 127)) >> 1;
            const unsigned short* gb = eIn + (crowBase >> 7) * (size_t)16384
                                     + (size_t)ilBase * 128;
            const int per = R * 16;
            for (int q = t; q < 2 * per; q += 512) {
                int cc = (q >= per) ? 1 : 0;
                int qq = q - cc * per;
                int il = qq >> 4, slot = qq & 15;
                int kc  = slot ^ (il & 15);
                int src = kc ^ ((ilBase + il) & 15);
                bf16x8 v = *(const bf16x8*)(gb + (size_t)cc * 8192 + il * 128 + src * 8);
                *(bf16x8*)&A_lds[cc][il][slot * 8] = v;
            }
        }
        {
            f32x4 a0 = {0,0,0,0}, a1 = {0,0,0,0};
            if (l4 == 0) {
                size_t row = rowBase + (size_t)(wrow * 16 + l15);
                size_t mx = rowBase + R - 1; if (row > mx) row = mx;
                const float* p = contO + row * 8;
                a0 = *(const f32x4*)p; a1 = *(const f32x4*)(p + 4);
            }
            bf16x8 cb = zeroA;
            if (l4 == 0) {
                #pragma unroll
                for (int e = 0; e < 4; ++e) {
                    ((unsigned short*)&cb)[e]     = f2bf(a0[e]);
                    ((unsigned short*)&cb)[e + 4] = f2bf(a1[e]);
                }
            } else if (l4 == 1) cb = onesA;
            const int i = wrow * 16 + l15;
            #pragma unroll
            for (int nfi = 0; nfi < 4; ++nfi) {
                int nf = wcolh * 4 + nfi;
                bf16x8 wv = zeroA;
                if (l4 < 2) wv = *(const bf16x8*)&wu_lds[nf][l4 * 16 + l15][0];
                f32x4 z = {0.f, 0.f, 0.f, 0.f};
                z = __builtin_amdgcn_mfma_f32_16x16x32_bf16(wv, cb, z, 0, 0, 0);
                u16x4 pk;
                #pragma unroll
                for (int r = 0; r < 4; ++r) pk[r] = f2bf(fmaxf(z[r], 0.f));
                int n4 = nf * 16 + l4 * 4;
                *(u16x4*)&u_lds[i][n4 ^ ((i & 15) << 3)] = pk;
            }
        }
        asm volatile("s_waitcnt lgkmcnt(0)" ::: "memory");
        __builtin_amdgcn_sched_barrier(0);
        __builtin_amdgcn_s_barrier();
        __builtin_amdgcn_sched_barrier(0);

        f32x4 acc[4];
        #pragma unroll
        for (int mf = 0; mf < 4; ++mf) acc[mf] = bh4;
        __builtin_amdgcn_s_setprio(1);
        #pragma unroll
        for (int kb = 0; kb < 8; ++kb) {
            bf16x8 af[4];
            #pragma unroll
            for (int mf = 0; mf < 4; ++mf) {
                int i = mf * 16 + l15;
                af[mf] = *(const bf16x8*)&A_lds[kb >> 2][i][((((kb & 3) * 4) + l4) ^ (i & 15)) * 8];
            }
            #pragma unroll
            for (int mf = 0; mf < 4; ++mf)
                acc[mf] = __builtin_amdgcn_mfma_f32_16x16x32_bf16(wreg[kb], af[mf], acc[mf], 0, 0, 0);
        }
        #pragma unroll
        for (int kb = 8; kb < 12; ++kb) {
            bf16x8 af[4];
            #pragma unroll
            for (int mf = 0; mf < 4; ++mf) {
                int i = mf * 16 + l15;
                af[mf] = *(const bf16x8*)&u_lds[i][((((kb - 8) * 4) + l4) ^ (i & 15)) * 8];
            }
            #pragma unroll
            for (int mf = 0; mf < 4; ++mf)
                acc[mf] = __builtin_amdgcn_mfma_f32_16x16x32_bf16(wreg[kb], af[mf], acc[mf], 0, 0, 0);
        }
        __builtin_amdgcn_s_setprio(0);
        if (j == 0) {
            #pragma unroll
            for (int mf = 0; mf < 4; ++mf) {
                int i = mf * 16 + l15;
                if (i < R) {
                    f32x4 o;
                    #pragma unroll
                    for (int r = 0; r < 4; ++r) o[r] = fmaxf(acc[mf][r], 0.f);
                    *(f32x4*)&outF[(rowBase + i) * 128 + wid * 16 + l4 * 4] = o;
                }
            }
        } else {
            #pragma unroll
            for (int mf = 0; mf < 4; ++mf) {
                int i = mf * 16 + l15;
                if (i < R) {
                    size_t Rg = rowBase + i;
                    int rr = (int)(Rg & 127), cc = rr & 1, il = rr >> 1;
                    u16x4 pk;
                    #pragma unroll
                    for (int r = 0; r < 4; ++r) pk[r] = f2bf(fmaxf(acc[mf][r], 0.f));
                    int n4 = wid * 16 + l4 * 4;
                    *(u16x4*)&eOut[(Rg >> 7) * 16384 + cc * 8192 + il * 128
                                   + (n4 ^ ((il & 15) << 3))] = pk;
                }
            }
        }
        asm volatile("s_waitcnt vmcnt(0) lgkmcnt(0)" ::: "memory");
        __builtin_amdgcn_sched_barrier(0);
        __builtin_amdgcn_s_barrier();
    }
    #undef RG
}

extern "C" void kernel_launch(void* const* d_in, const int* in_sizes, int n_in,
                              void* d_out, int out_size, void* d_ws, size_t ws_size,
                              hipStream_t stream) {
    const float* c[10];
    for (int j = 0; j < 10; ++j) c[j] = (const float*)d_in[j];
    const float* Wu = (const float*)d_in[19];
    const float* bu = (const float*)d_in[20];
    const float* Wh = (const float*)d_in[21];
    const float* bh = (const float*)d_in[22];

    unsigned short* Wbf   = (unsigned short*)d_ws;                       // 96 KiB (1 MiB pad)
    unsigned short* tbase = (unsigned short*)((char*)d_ws + (1u << 20)); // per-level regions

    k_cvtW<<<128, 384, 0, stream>>>(Wh, Wbf);
    k_main<<<512, 512, 0, stream>>>(c[0], c[1], c[2], c[3], c[4], c[5], c[6], c[7],
                                    c[8], c[9], Wbf, Wu, bu, bh, tbase, (float*)d_out);
}

// Round 23
// 107.022 us; speedup vs baseline: 3.5731x; 1.0795x over previous
//
#include <hip/hip_runtime.h>
#include <hip/hip_bf16.h>

typedef __attribute__((ext_vector_type(8))) short bf16x8;
typedef __attribute__((ext_vector_type(4))) float f32x4;
typedef __attribute__((ext_vector_type(4))) unsigned short u16x4;

__device__ __forceinline__ unsigned short f2bf(float f) {
    __hip_bfloat16 h = __float2bfloat16(f);   // RTNE; pairs fuse to v_cvt_pk_bf16_f32
    union { __hip_bfloat16 h; unsigned short u; } v; v.h = h;
    return v.u;
}

__device__ __forceinline__ void cp16_g2l(const void* g, void* l) {
    __builtin_amdgcn_global_load_lds(
        (const __attribute__((address_space(1))) unsigned int*)g,
        (__attribute__((address_space(3))) unsigned int*)l, 16, 0, 0);
}

// ---- one-time: W_h f32 [128][384] -> plain bf16 row-major image in ws ----
__global__ __launch_bounds__(384) void k_cvtW(const float* __restrict__ Wh,
                                              unsigned short* __restrict__ Wbf) {
    int n = blockIdx.x, k = threadIdx.x;
    Wbf[n * 384 + k] = f2bf(Wh[n * 384 + k]);
}

// =====================================================================
// Whole-tree kernel (r17 config + 3-level T5 priority hierarchy).
// 512 blocks; block b owns rows [b*R_j,(b+1)*R_j) at every level,
// R_j = 2<<j; disjoint ws regions; intra-block level drains.
// Priority hierarchy for cross-block CU arbitration (2 blocks/CU):
//   prio 2: main-GEMM ds_read+MFMA clusters
//   prio 1: u-phase / child-u MFMA clusters
//   prio 0: staging (DMA issue, contents loads), epilogue, prologue
// r22 measured binary setprio at -8%; this refines the same mechanism.
// launch_bounds (512,4) — tighter caps spill (r19); G=1024 halves
// pipeline depth (r20); LDS L8->L7 fusion serializes (r18).
// Transposed compute, &15 XOR swizzle, counted vmcnt(6) A-DMA pipeline.
// =====================================================================
__global__ __launch_bounds__(512, 4) void k_main(
    const float* __restrict__ c0, const float* __restrict__ c1,
    const float* __restrict__ c2, const float* __restrict__ c3,
    const float* __restrict__ c4, const float* __restrict__ c5,
    const float* __restrict__ c6, const float* __restrict__ c7,
    const float* __restrict__ c8, const float* __restrict__ c9,
    const unsigned short* __restrict__ Wbf,
    const float* __restrict__ Wu, const float* __restrict__ bu,
    const float* __restrict__ bh,
    unsigned short* __restrict__ tbase,
    float* __restrict__ outF)
{
    __shared__ __align__(16) unsigned short A_lds[2][64][128]; // [cc][il][n^swz16]
    __shared__ __align__(16) unsigned short u_lds[64][128];    // [i][n^swz16]
    __shared__ __align__(16) unsigned short wu_lds[8][32][8];

    const int t = threadIdx.x, lane = t & 63, wid = t >> 6;    // 8 waves
    const int l15 = lane & 15, l4 = lane >> 4;
    const int wrow = wid & 3;
    const int wcolh = wid >> 2;
    const int b = blockIdx.x;

    // ---- persistent W fragments: wave's 16-col slice (48 VGPR, pinned) ----
    bf16x8 wreg[12];
    {
        int n = wid * 16 + l15;
        #pragma unroll
        for (int kb = 0; kb < 12; ++kb)
            wreg[kb] = *reinterpret_cast<const bf16x8*>(Wbf + n * 384 + kb * 32 + l4 * 8);
    }
    #pragma unroll
    for (int kb = 0; kb < 12; ++kb)
        asm volatile("" : "+v"(wreg[kb]));

    if (wid == 0 && l4 < 2) {
        #pragma unroll
        for (int nf = 0; nf < 8; ++nf) {
            int n = nf * 16 + l15;
            bf16x8 v = {0, 0, 0, 0, 0, 0, 0, 0};
            if (l4 == 0) {
                #pragma unroll
                for (int k = 0; k < 8; ++k) ((unsigned short*)&v)[k] = f2bf(Wu[n * 8 + k]);
            } else {
                ((unsigned short*)&v)[0] = f2bf(bu[n]);
            }
            *(bf16x8*)&wu_lds[nf][l4 * 16 + l15][0] = v;
        }
    }
    const f32x4 bh4 = *(const f32x4*)&bh[wid * 16 + l4 * 4];

    bf16x8 zeroA = {0, 0, 0, 0, 0, 0, 0, 0};
    bf16x8 onesA = zeroA; ((unsigned short*)&onesA)[0] = 0x3F80;

    __syncthreads();  // wu_lds visible

    // region pointer for level j's emb output
    #define RG(j) (tbase + (size_t)131072 * (512 - (2 << (j))))

    f32x4 cO0 = {0,0,0,0}, cO1 = {0,0,0,0};

    // ================= LEVEL 8 (leaf): T=8 full tiles =================
    {
        const int T = 8;
        const int tb = b * T;
        unsigned short* eOut = RG(8);
        if (l4 == 0) {
            const float* p = c8 + ((size_t)tb * 64 + wrow * 16 + l15) * 8;
            cO0 = *(const f32x4*)p; cO1 = *(const f32x4*)(p + 4);
        }
        for (int tt = 0; tt < T; ++tt) {
            const int tile = tb + tt;
            // ---- u-phase (prio 1) ----
            {
                bf16x8 cb = zeroA;
                if (l4 == 0) {
                    #pragma unroll
                    for (int e = 0; e < 4; ++e) {
                        ((unsigned short*)&cb)[e]     = f2bf(cO0[e]);
                        ((unsigned short*)&cb)[e + 4] = f2bf(cO1[e]);
                    }
                } else if (l4 == 1) cb = onesA;
                const int i = wrow * 16 + l15;
                __builtin_amdgcn_s_setprio(1);
                #pragma unroll
                for (int nfi = 0; nfi < 4; ++nfi) {
                    int nf = wcolh * 4 + nfi;
                    bf16x8 wv = zeroA;
                    if (l4 < 2) wv = *(const bf16x8*)&wu_lds[nf][l4 * 16 + l15][0];
                    f32x4 z = {0.f, 0.f, 0.f, 0.f};
                    z = __builtin_amdgcn_mfma_f32_16x16x32_bf16(wv, cb, z, 0, 0, 0);
                    u16x4 pk;
                    #pragma unroll
                    for (int r = 0; r < 4; ++r) pk[r] = f2bf(fmaxf(z[r], 0.f));
                    int n4 = nf * 16 + l4 * 4;
                    *(u16x4*)&u_lds[i][n4 ^ ((i & 15) << 3)] = pk;
                }
                __builtin_amdgcn_s_setprio(0);
            }
            // ---- child-u: direct loads (prio 0) then MFMA cluster (prio 1) ----
            {
                const float* pcBase = c9 + ((size_t)tile * 128 + wrow * 32 + l15) * 8;
                #pragma unroll
                for (int rb = 0; rb < 2; ++rb) {
                    bf16x8 cb = zeroA;
                    if (l4 == 0) {
                        f32x4 a  = *(const f32x4*)(pcBase + rb * 128);
                        f32x4 b2 = *(const f32x4*)(pcBase + rb * 128 + 4);
                        #pragma unroll
                        for (int e = 0; e < 4; ++e) {
                            ((unsigned short*)&cb)[e]     = f2bf(a[e]);
                            ((unsigned short*)&cb)[e + 4] = f2bf(b2[e]);
                        }
                    } else if (l4 == 1) cb = onesA;
                    const int rr = wrow * 32 + rb * 16 + l15;
                    const int cc = rr & 1, il = rr >> 1;
                    __builtin_amdgcn_s_setprio(1);
                    #pragma unroll
                    for (int nfi = 0; nfi < 4; ++nfi) {
                        int nf = wcolh * 4 + nfi;
                        bf16x8 wv = zeroA;
                        if (l4 < 2) wv = *(const bf16x8*)&wu_lds[nf][l4 * 16 + l15][0];
                        f32x4 z = {0.f, 0.f, 0.f, 0.f};
                        z = __builtin_amdgcn_mfma_f32_16x16x32_bf16(wv, cb, z, 0, 0, 0);
                        u16x4 pk;
                        #pragma unroll
                        for (int r = 0; r < 4; ++r) pk[r] = f2bf(fmaxf(z[r], 0.f));
                        int n4 = nf * 16 + l4 * 4;
                        *(u16x4*)&A_lds[cc][il][n4 ^ ((il & 15) << 3)] = pk;
                    }
                    __builtin_amdgcn_s_setprio(0);
                }
            }
            // ---- prefetch next tile's contents (clamped, prio 0) ----
            {
                int tn = (tt + 1 < T) ? tile + 1 : tile;
                if (l4 == 0) {
                    const float* p = c8 + ((size_t)tn * 64 + wrow * 16 + l15) * 8;
                    cO0 = *(const f32x4*)p; cO1 = *(const f32x4*)(p + 4);
                }
            }
            asm volatile("s_waitcnt lgkmcnt(0)" ::: "memory");
            __builtin_amdgcn_sched_barrier(0);
            __builtin_amdgcn_s_barrier();
            __builtin_amdgcn_sched_barrier(0);

            f32x4 acc[4];
            #pragma unroll
            for (int mf = 0; mf < 4; ++mf) acc[mf] = bh4;
            __builtin_amdgcn_s_setprio(2);
            #pragma unroll
            for (int kb = 0; kb < 8; ++kb) {
                bf16x8 af[4];
                #pragma unroll
                for (int mf = 0; mf < 4; ++mf) {
                    int i = mf * 16 + l15;
                    af[mf] = *(const bf16x8*)&A_lds[kb >> 2][i][((((kb & 3) * 4) + l4) ^ (i & 15)) * 8];
                }
                #pragma unroll
                for (int mf = 0; mf < 4; ++mf)
                    acc[mf] = __builtin_amdgcn_mfma_f32_16x16x32_bf16(wreg[kb], af[mf], acc[mf], 0, 0, 0);
            }
            #pragma unroll
            for (int kb = 8; kb < 12; ++kb) {
                bf16x8 af[4];
                #pragma unroll
                for (int mf = 0; mf < 4; ++mf) {
                    int i = mf * 16 + l15;
                    af[mf] = *(const bf16x8*)&u_lds[i][((((kb - 8) * 4) + l4) ^ (i & 15)) * 8];
                }
                #pragma unroll
                for (int mf = 0; mf < 4; ++mf)
                    acc[mf] = __builtin_amdgcn_mfma_f32_16x16x32_bf16(wreg[kb], af[mf], acc[mf], 0, 0, 0);
            }
            __builtin_amdgcn_s_setprio(0);
            #pragma unroll
            for (int mf = 0; mf < 4; ++mf) {
                int i = mf * 16 + l15;
                int Rg = tile * 64 + i;
                int rr = Rg & 127, cc = rr & 1, il = rr >> 1;
                u16x4 pk;
                #pragma unroll
                for (int r = 0; r < 4; ++r) pk[r] = f2bf(fmaxf(acc[mf][r], 0.f));
                int n4 = wid * 16 + l4 * 4;
                *(u16x4*)&eOut[(size_t)(Rg >> 7) * 16384 + cc * 8192 + il * 128
                               + (n4 ^ ((il & 15) << 3))] = pk;
            }
            asm volatile("s_waitcnt lgkmcnt(0)" ::: "memory");
            __builtin_amdgcn_sched_barrier(0);
            __builtin_amdgcn_s_barrier();
        }
        asm volatile("s_waitcnt vmcnt(0) lgkmcnt(0)" ::: "memory");
        __builtin_amdgcn_sched_barrier(0);
        __builtin_amdgcn_s_barrier();
    }

    // ================= LEVELS 7..5: full-tile DMA levels =================
    for (int j = 7; j >= 5; --j) {
        const int T = 1 << (j - 5);     // 4, 2, 1
        const int tb = b * T;
        const float* contO = (j == 7) ? c7 : (j == 6) ? c6 : c5;
        const unsigned short* eIn = RG(j + 1);
        unsigned short* eOut = RG(j);

        {
            const unsigned short* src = eIn + (size_t)tb * 16384;
            #pragma unroll
            for (int it = 0; it < 4; ++it) {
                int q = t + it * 512;
                cp16_g2l(src + q * 8, &A_lds[0][0][0] + q * 8);
            }
            if (l4 == 0) {
                const float* p = contO + ((size_t)tb * 64 + wrow * 16 + l15) * 8;
                cO0 = *(const f32x4*)p; cO1 = *(const f32x4*)(p + 4);
            }
        }
        __syncthreads();

        for (int tt = 0; tt < T; ++tt) {
            const int tile = tb + tt;
            {
                bf16x8 cb = zeroA;
                if (l4 == 0) {
                    #pragma unroll
                    for (int e = 0; e < 4; ++e) {
                        ((unsigned short*)&cb)[e]     = f2bf(cO0[e]);
                        ((unsigned short*)&cb)[e + 4] = f2bf(cO1[e]);
                    }
                } else if (l4 == 1) cb = onesA;
                const int i = wrow * 16 + l15;
                __builtin_amdgcn_s_setprio(1);
                #pragma unroll
                for (int nfi = 0; nfi < 4; ++nfi) {
                    int nf = wcolh * 4 + nfi;
                    bf16x8 wv = zeroA;
                    if (l4 < 2) wv = *(const bf16x8*)&wu_lds[nf][l4 * 16 + l15][0];
                    f32x4 z = {0.f, 0.f, 0.f, 0.f};
                    z = __builtin_amdgcn_mfma_f32_16x16x32_bf16(wv, cb, z, 0, 0, 0);
                    u16x4 pk;
                    #pragma unroll
                    for (int r = 0; r < 4; ++r) pk[r] = f2bf(fmaxf(z[r], 0.f));
                    int n4 = nf * 16 + l4 * 4;
                    *(u16x4*)&u_lds[i][n4 ^ ((i & 15) << 3)] = pk;
                }
                __builtin_amdgcn_s_setprio(0);
            }
            {
                int tn = (tt + 1 < T) ? tile + 1 : tile;
                if (l4 == 0) {
                    const float* p = contO + ((size_t)tn * 64 + wrow * 16 + l15) * 8;
                    cO0 = *(const f32x4*)p; cO1 = *(const f32x4*)(p + 4);
                }
            }
            asm volatile("s_waitcnt vmcnt(6)" ::: "memory");  // drain 4 DMA; leave 4 stores + 2 loads
            asm volatile("s_waitcnt lgkmcnt(0)" ::: "memory");
            __builtin_amdgcn_sched_barrier(0);
            __builtin_amdgcn_s_barrier();
            __builtin_amdgcn_sched_barrier(0);

            f32x4 acc[4];
            #pragma unroll
            for (int mf = 0; mf < 4; ++mf) acc[mf] = bh4;
            __builtin_amdgcn_s_setprio(2);
            #pragma unroll
            for (int kb = 0; kb < 8; ++kb) {
                bf16x8 af[4];
                #pragma unroll
                for (int mf = 0; mf < 4; ++mf) {
                    int i = mf * 16 + l15;
                    af[mf] = *(const bf16x8*)&A_lds[kb >> 2][i][((((kb & 3) * 4) + l4) ^ (i & 15)) * 8];
                }
                #pragma unroll
                for (int mf = 0; mf < 4; ++mf)
                    acc[mf] = __builtin_amdgcn_mfma_f32_16x16x32_bf16(wreg[kb], af[mf], acc[mf], 0, 0, 0);
            }
            __builtin_amdgcn_s_setprio(0);
            asm volatile("s_waitcnt lgkmcnt(0)" ::: "memory");
            __builtin_amdgcn_sched_barrier(0);
            __builtin_amdgcn_s_barrier();
            __builtin_amdgcn_sched_barrier(0);
            if (tt + 1 < T) {
                const unsigned short* src = eIn + (size_t)(tile + 1) * 16384;
                #pragma unroll
                for (int it = 0; it < 4; ++it) {
                    int q = t + it * 512;
                    cp16_g2l(src + q * 8, &A_lds[0][0][0] + q * 8);
                }
            }
            __builtin_amdgcn_s_setprio(2);
            #pragma unroll
            for (int kb = 8; kb < 12; ++kb) {
                bf16x8 af[4];
                #pragma unroll
                for (int mf = 0; mf < 4; ++mf) {
                    int i = mf * 16 + l15;
                    af[mf] = *(const bf16x8*)&u_lds[i][((((kb - 8) * 4) + l4) ^ (i & 15)) * 8];
                }
                #pragma unroll
                for (int mf = 0; mf < 4; ++mf)
                    acc[mf] = __builtin_amdgcn_mfma_f32_16x16x32_bf16(wreg[kb], af[mf], acc[mf], 0, 0, 0);
            }
            __builtin_amdgcn_s_setprio(0);
            #pragma unroll
            for (int mf = 0; mf < 4; ++mf) {
                int i = mf * 16 + l15;
                int Rg = tile * 64 + i;
                int rr = Rg & 127, cc = rr & 1, il = rr >> 1;
                u16x4 pk;
                #pragma unroll
                for (int r = 0; r < 4; ++r) pk[r] = f2bf(fmaxf(acc[mf][r], 0.f));
                int n4 = wid * 16 + l4 * 4;
                *(u16x4*)&eOut[(size_t)(Rg >> 7) * 16384 + cc * 8192 + il * 128
                               + (n4 ^ ((il & 15) << 3))] = pk;
            }
            asm volatile("s_waitcnt lgkmcnt(0)" ::: "memory");
            __builtin_amdgcn_sched_barrier(0);
            __builtin_amdgcn_s_barrier();
        }
        asm volatile("s_waitcnt vmcnt(0) lgkmcnt(0)" ::: "memory");
        __builtin_amdgcn_sched_barrier(0);
        __builtin_amdgcn_s_barrier();
    }

    // ================= LEVELS 4..0: partial (reg-staged) =================
    for (int j = 4; j >= 0; --j) {
        const int R = 2 << j;            // 32..2
        const float* contO = (j == 4) ? c4 : (j == 3) ? c3 : (j == 2) ? c2
                           : (j == 1) ? c1 : c0;
        const unsigned short* eIn = RG(j + 1);
        unsigned short* eOut = (j > 0) ? RG(j) : nullptr;

        const size_t rowBase  = (size_t)b * (size_t)R;
        const size_t crowBase = rowBase * 2;

        {
            const int ilBase = ((int)(crowBase & 127)) >> 1;
            const unsigned short* gb = eIn + (crowBase >> 7) * (size_t)16384
                                     + (size_t)ilBase * 128;
            const int per = R * 16;
            for (int q = t; q < 2 * per; q += 512) {
                int cc = (q >= per) ? 1 : 0;
                int qq = q - cc * per;
                int il = qq >> 4, slot = qq & 15;
                int kc  = slot ^ (il & 15);
                int src = kc ^ ((ilBase + il) & 15);
                bf16x8 v = *(const bf16x8*)(gb + (size_t)cc * 8192 + il * 128 + src * 8);
                *(bf16x8*)&A_lds[cc][il][slot * 8] = v;
            }
        }
        {
            f32x4 a0 = {0,0,0,0}, a1 = {0,0,0,0};
            if (l4 == 0) {
                size_t row = rowBase + (size_t)(wrow * 16 + l15);
                size_t mx = rowBase + R - 1; if (row > mx) row = mx;
                const float* p = contO + row * 8;
                a0 = *(const f32x4*)p; a1 = *(const f32x4*)(p + 4);
            }
            bf16x8 cb = zeroA;
            if (l4 == 0) {
                #pragma unroll
                for (int e = 0; e < 4; ++e) {
                    ((unsigned short*)&cb)[e]     = f2bf(a0[e]);
                    ((unsigned short*)&cb)[e + 4] = f2bf(a1[e]);
                }
            } else if (l4 == 1) cb = onesA;
            const int i = wrow * 16 + l15;
            __builtin_amdgcn_s_setprio(1);
            #pragma unroll
            for (int nfi = 0; nfi < 4; ++nfi) {
                int nf = wcolh * 4 + nfi;
                bf16x8 wv = zeroA;
                if (l4 < 2) wv = *(const bf16x8*)&wu_lds[nf][l4 * 16 + l15][0];
                f32x4 z = {0.f, 0.f, 0.f, 0.f};
                z = __builtin_amdgcn_mfma_f32_16x16x32_bf16(wv, cb, z, 0, 0, 0);
                u16x4 pk;
                #pragma unroll
                for (int r = 0; r < 4; ++r) pk[r] = f2bf(fmaxf(z[r], 0.f));
                int n4 = nf * 16 + l4 * 4;
                *(u16x4*)&u_lds[i][n4 ^ ((i & 15) << 3)] = pk;
            }
            __builtin_amdgcn_s_setprio(0);
        }
        asm volatile("s_waitcnt lgkmcnt(0)" ::: "memory");
        __builtin_amdgcn_sched_barrier(0);
        __builtin_amdgcn_s_barrier();
        __builtin_amdgcn_sched_barrier(0);

        f32x4 acc[4];
        #pragma unroll
        for (int mf = 0; mf < 4; ++mf) acc[mf] = bh4;
        __builtin_amdgcn_s_setprio(2);
        #pragma unroll
        for (int kb = 0; kb < 8; ++kb) {
            bf16x8 af[4];
            #pragma unroll
            for (int mf = 0; mf < 4; ++mf) {
                int i = mf * 16 + l15;
                af[mf] = *(const bf16x8*)&A_lds[kb >> 2][i][((((kb & 3) * 4) + l4) ^ (i & 15)) * 8];
            }
            #pragma unroll
            for (int mf = 0; mf < 4; ++mf)
                acc[mf] = __builtin_amdgcn_mfma_f32_16x16x32_bf16(wreg[kb], af[mf], acc[mf], 0, 0, 0);
        }
        #pragma unroll
        for (int kb = 8; kb < 12; ++kb) {
            bf16x8 af[4];
            #pragma unroll
            for (int mf = 0; mf < 4; ++mf) {
                int i = mf * 16 + l15;
                af[mf] = *(const bf16x8*)&u_lds[i][((((kb - 8) * 4) + l4) ^ (i & 15)) * 8];
            }
            #pragma unroll
            for (int mf = 0; mf < 4; ++mf)
                acc[mf] = __builtin_amdgcn_mfma_f32_16x16x32_bf16(wreg[kb], af[mf], acc[mf], 0, 0, 0);
        }
        __builtin_amdgcn_s_setprio(0);
        if (j == 0) {
            #pragma unroll
            for (int mf = 0; mf < 4; ++mf) {
                int i = mf * 16 + l15;
                if (i < R) {
                    f32x4 o;
                    #pragma unroll
                    for (int r = 0; r < 4; ++r) o[r] = fmaxf(acc[mf][r], 0.f);
                    *(f32x4*)&outF[(rowBase + i) * 128 + wid * 16 + l4 * 4] = o;
                }
            }
        } else {
            #pragma unroll
            for (int mf = 0; mf < 4; ++mf) {
                int i = mf * 16 + l15;
                if (i < R) {
                    size_t Rg = rowBase + i;
                    int rr = (int)(Rg & 127), cc = rr & 1, il = rr >> 1;
                    u16x4 pk;
                    #pragma unroll
                    for (int r = 0; r < 4; ++r) pk[r] = f2bf(fmaxf(acc[mf][r], 0.f));
                    int n4 = wid * 16 + l4 * 4;
                    *(u16x4*)&eOut[(Rg >> 7) * 16384 + cc * 8192 + il * 128
                                   + (n4 ^ ((il & 15) << 3))] = pk;
                }
            }
        }
        asm volatile("s_waitcnt vmcnt(0) lgkmcnt(0)" ::: "memory");
        __builtin_amdgcn_sched_barrier(0);
        __builtin_amdgcn_s_barrier();
    }
    #undef RG
}

extern "C" void kernel_launch(void* const* d_in, const int* in_sizes, int n_in,
                              void* d_out, int out_size, void* d_ws, size_t ws_size,
                              hipStream_t stream) {
    const float* c[10];
    for (int j = 0; j < 10; ++j) c[j] = (const float*)d_in[j];
    const float* Wu = (const float*)d_in[19];
    const float* bu = (const float*)d_in[20];
    const float* Wh = (const float*)d_in[21];
    const float* bh = (const float*)d_in[22];

    unsigned short* Wbf   = (unsigned short*)d_ws;                       // 96 KiB (1 MiB pad)
    unsigned short* tbase = (unsigned short*)((char*)d_ws + (1u << 20)); // per-level regions

    k_cvtW<<<128, 384, 0, stream>>>(Wh, Wbf);
    k_main<<<512, 512, 0, stream>>>(c[0], c[1], c[2], c[3], c[4], c[5], c[6], c[7],
                                    c[8], c[9], Wbf, Wu, bu, bh, tbase, (float*)d_out);
}

// Round 24
// 104.577 us; speedup vs baseline: 3.6567x; 1.0234x over previous
//
#include <hip/hip_runtime.h>
#include <hip/hip_bf16.h>

typedef __attribute__((ext_vector_type(8))) short bf16x8;
typedef __attribute__((ext_vector_type(4))) float f32x4;
typedef __attribute__((ext_vector_type(4))) unsigned short u16x4;

__device__ __forceinline__ unsigned short f2bf(float f) {
    __hip_bfloat16 h = __float2bfloat16(f);   // RTNE; pairs fuse to v_cvt_pk_bf16_f32
    union { __hip_bfloat16 h; unsigned short u; } v; v.h = h;
    return v.u;
}

__device__ __forceinline__ void cp16_g2l(const void* g, void* l) {
    __builtin_amdgcn_global_load_lds(
        (const __attribute__((address_space(1))) unsigned int*)g,
        (__attribute__((address_space(3))) unsigned int*)l, 16, 0, 0);
}

// ---- one-time: W_h f32 [128][384] -> plain bf16 row-major image in ws ----
__global__ __launch_bounds__(384) void k_cvtW(const float* __restrict__ Wh,
                                              unsigned short* __restrict__ Wbf) {
    int n = blockIdx.x, k = threadIdx.x;
    Wbf[n * 384 + k] = f2bf(Wh[n * 384 + k]);
}

// =====================================================================
// Whole-tree kernel (r23 config + T14 issue-early on leaf child loads).
// 512 blocks; block b owns rows [b*R_j,(b+1)*R_j) at every level,
// R_j = 2<<j; disjoint ws regions; intra-block level drains.
// Priority hierarchy for cross-block CU arbitration (2 blocks/CU):
//   prio 2: main-GEMM ds_read+MFMA clusters
//   prio 1: u-phase / child-u MFMA clusters
//   prio 0: staging (DMA issue, contents loads), epilogue, prologue
// Leaf child-contents (c9) loads issued BEFORE the u-phase (short-lived
// regs, live across 4 MFMAs only) so their HBM/L2 latency hides under
// the u-phase MFMA cluster instead of stalling the child-u pack.
// launch_bounds (512,4) — tighter caps spill (r19); G=1024 halves
// pipeline depth (r20); LDS L8->L7 fusion serializes (r18).
// Transposed compute, &15 XOR swizzle, counted vmcnt(6) A-DMA pipeline.
// =====================================================================
__global__ __launch_bounds__(512, 4) void k_main(
    const float* __restrict__ c0, const float* __restrict__ c1,
    const float* __restrict__ c2, const float* __restrict__ c3,
    const float* __restrict__ c4, const float* __restrict__ c5,
    const float* __restrict__ c6, const float* __restrict__ c7,
    const float* __restrict__ c8, const float* __restrict__ c9,
    const unsigned short* __restrict__ Wbf,
    const float* __restrict__ Wu, const float* __restrict__ bu,
    const float* __restrict__ bh,
    unsigned short* __restrict__ tbase,
    float* __restrict__ outF)
{
    __shared__ __align__(16) unsigned short A_lds[2][64][128]; // [cc][il][n^swz16]
    __shared__ __align__(16) unsigned short u_lds[64][128];    // [i][n^swz16]
    __shared__ __align__(16) unsigned short wu_lds[8][32][8];

    const int t = threadIdx.x, lane = t & 63, wid = t >> 6;    // 8 waves
    const int l15 = lane & 15, l4 = lane >> 4;
    const int wrow = wid & 3;
    const int wcolh = wid >> 2;
    const int b = blockIdx.x;

    // ---- persistent W fragments: wave's 16-col slice (48 VGPR, pinned) ----
    bf16x8 wreg[12];
    {
        int n = wid * 16 + l15;
        #pragma unroll
        for (int kb = 0; kb < 12; ++kb)
            wreg[kb] = *reinterpret_cast<const bf16x8*>(Wbf + n * 384 + kb * 32 + l4 * 8);
    }
    #pragma unroll
    for (int kb = 0; kb < 12; ++kb)
        asm volatile("" : "+v"(wreg[kb]));

    if (wid == 0 && l4 < 2) {
        #pragma unroll
        for (int nf = 0; nf < 8; ++nf) {
            int n = nf * 16 + l15;
            bf16x8 v = {0, 0, 0, 0, 0, 0, 0, 0};
            if (l4 == 0) {
                #pragma unroll
                for (int k = 0; k < 8; ++k) ((unsigned short*)&v)[k] = f2bf(Wu[n * 8 + k]);
            } else {
                ((unsigned short*)&v)[0] = f2bf(bu[n]);
            }
            *(bf16x8*)&wu_lds[nf][l4 * 16 + l15][0] = v;
        }
    }
    const f32x4 bh4 = *(const f32x4*)&bh[wid * 16 + l4 * 4];

    bf16x8 zeroA = {0, 0, 0, 0, 0, 0, 0, 0};
    bf16x8 onesA = zeroA; ((unsigned short*)&onesA)[0] = 0x3F80;

    __syncthreads();  // wu_lds visible

    // region pointer for level j's emb output
    #define RG(j) (tbase + (size_t)131072 * (512 - (2 << (j))))

    f32x4 cO0 = {0,0,0,0}, cO1 = {0,0,0,0};

    // ================= LEVEL 8 (leaf): T=8 full tiles =================
    {
        const int T = 8;
        const int tb = b * T;
        unsigned short* eOut = RG(8);
        if (l4 == 0) {
            const float* p = c8 + ((size_t)tb * 64 + wrow * 16 + l15) * 8;
            cO0 = *(const f32x4*)p; cO1 = *(const f32x4*)(p + 4);
        }
        for (int tt = 0; tt < T; ++tt) {
            const int tile = tb + tt;
            // ---- T14 issue-early: child contents loads BEFORE the u-phase ----
            f32x4 cC00 = {0,0,0,0}, cC01 = {0,0,0,0}, cC10 = {0,0,0,0}, cC11 = {0,0,0,0};
            if (l4 == 0) {
                const float* pcBase = c9 + ((size_t)tile * 128 + wrow * 32 + l15) * 8;
                cC00 = *(const f32x4*)pcBase;         cC01 = *(const f32x4*)(pcBase + 4);
                cC10 = *(const f32x4*)(pcBase + 128); cC11 = *(const f32x4*)(pcBase + 132);
            }
            // ---- u-phase (prio 1): covers the child-load latency ----
            {
                bf16x8 cb = zeroA;
                if (l4 == 0) {
                    #pragma unroll
                    for (int e = 0; e < 4; ++e) {
                        ((unsigned short*)&cb)[e]     = f2bf(cO0[e]);
                        ((unsigned short*)&cb)[e + 4] = f2bf(cO1[e]);
                    }
                } else if (l4 == 1) cb = onesA;
                const int i = wrow * 16 + l15;
                __builtin_amdgcn_s_setprio(1);
                #pragma unroll
                for (int nfi = 0; nfi < 4; ++nfi) {
                    int nf = wcolh * 4 + nfi;
                    bf16x8 wv = zeroA;
                    if (l4 < 2) wv = *(const bf16x8*)&wu_lds[nf][l4 * 16 + l15][0];
                    f32x4 z = {0.f, 0.f, 0.f, 0.f};
                    z = __builtin_amdgcn_mfma_f32_16x16x32_bf16(wv, cb, z, 0, 0, 0);
                    u16x4 pk;
                    #pragma unroll
                    for (int r = 0; r < 4; ++r) pk[r] = f2bf(fmaxf(z[r], 0.f));
                    int n4 = nf * 16 + l4 * 4;
                    *(u16x4*)&u_lds[i][n4 ^ ((i & 15) << 3)] = pk;
                }
                __builtin_amdgcn_s_setprio(0);
            }
            // ---- child-u: consume prefetched regs (prio 1 clusters) ----
            {
                #pragma unroll
                for (int rb = 0; rb < 2; ++rb) {
                    bf16x8 cb = zeroA;
                    if (l4 == 0) {
                        f32x4 a  = rb ? cC10 : cC00;
                        f32x4 b2 = rb ? cC11 : cC01;
                        #pragma unroll
                        for (int e = 0; e < 4; ++e) {
                            ((unsigned short*)&cb)[e]     = f2bf(a[e]);
                            ((unsigned short*)&cb)[e + 4] = f2bf(b2[e]);
                        }
                    } else if (l4 == 1) cb = onesA;
                    const int rr = wrow * 32 + rb * 16 + l15;
                    const int cc = rr & 1, il = rr >> 1;
                    __builtin_amdgcn_s_setprio(1);
                    #pragma unroll
                    for (int nfi = 0; nfi < 4; ++nfi) {
                        int nf = wcolh * 4 + nfi;
                        bf16x8 wv = zeroA;
                        if (l4 < 2) wv = *(const bf16x8*)&wu_lds[nf][l4 * 16 + l15][0];
                        f32x4 z = {0.f, 0.f, 0.f, 0.f};
                        z = __builtin_amdgcn_mfma_f32_16x16x32_bf16(wv, cb, z, 0, 0, 0);
                        u16x4 pk;
                        #pragma unroll
                        for (int r = 0; r < 4; ++r) pk[r] = f2bf(fmaxf(z[r], 0.f));
                        int n4 = nf * 16 + l4 * 4;
                        *(u16x4*)&A_lds[cc][il][n4 ^ ((il & 15) << 3)] = pk;
                    }
                    __builtin_amdgcn_s_setprio(0);
                }
            }
            // ---- prefetch next tile's own contents (clamped, prio 0) ----
            {
                int tn = (tt + 1 < T) ? tile + 1 : tile;
                if (l4 == 0) {
                    const float* p = c8 + ((size_t)tn * 64 + wrow * 16 + l15) * 8;
                    cO0 = *(const f32x4*)p; cO1 = *(const f32x4*)(p + 4);
                }
            }
            asm volatile("s_waitcnt lgkmcnt(0)" ::: "memory");
            __builtin_amdgcn_sched_barrier(0);
            __builtin_amdgcn_s_barrier();
            __builtin_amdgcn_sched_barrier(0);

            f32x4 acc[4];
            #pragma unroll
            for (int mf = 0; mf < 4; ++mf) acc[mf] = bh4;
            __builtin_amdgcn_s_setprio(2);
            #pragma unroll
            for (int kb = 0; kb < 8; ++kb) {
                bf16x8 af[4];
                #pragma unroll
                for (int mf = 0; mf < 4; ++mf) {
                    int i = mf * 16 + l15;
                    af[mf] = *(const bf16x8*)&A_lds[kb >> 2][i][((((kb & 3) * 4) + l4) ^ (i & 15)) * 8];
                }
                #pragma unroll
                for (int mf = 0; mf < 4; ++mf)
                    acc[mf] = __builtin_amdgcn_mfma_f32_16x16x32_bf16(wreg[kb], af[mf], acc[mf], 0, 0, 0);
            }
            #pragma unroll
            for (int kb = 8; kb < 12; ++kb) {
                bf16x8 af[4];
                #pragma unroll
                for (int mf = 0; mf < 4; ++mf) {
                    int i = mf * 16 + l15;
                    af[mf] = *(const bf16x8*)&u_lds[i][((((kb - 8) * 4) + l4) ^ (i & 15)) * 8];
                }
                #pragma unroll
                for (int mf = 0; mf < 4; ++mf)
                    acc[mf] = __builtin_amdgcn_mfma_f32_16x16x32_bf16(wreg[kb], af[mf], acc[mf], 0, 0, 0);
            }
            __builtin_amdgcn_s_setprio(0);
            #pragma unroll
            for (int mf = 0; mf < 4; ++mf) {
                int i = mf * 16 + l15;
                int Rg = tile * 64 + i;
                int rr = Rg & 127, cc = rr & 1, il = rr >> 1;
                u16x4 pk;
                #pragma unroll
                for (int r = 0; r < 4; ++r) pk[r] = f2bf(fmaxf(acc[mf][r], 0.f));
                int n4 = wid * 16 + l4 * 4;
                *(u16x4*)&eOut[(size_t)(Rg >> 7) * 16384 + cc * 8192 + il * 128
                               + (n4 ^ ((il & 15) << 3))] = pk;
            }
            asm volatile("s_waitcnt lgkmcnt(0)" ::: "memory");
            __builtin_amdgcn_sched_barrier(0);
            __builtin_amdgcn_s_barrier();
        }
        asm volatile("s_waitcnt vmcnt(0) lgkmcnt(0)" ::: "memory");
        __builtin_amdgcn_sched_barrier(0);
        __builtin_amdgcn_s_barrier();
    }

    // ================= LEVELS 7..5: full-tile DMA levels =================
    for (int j = 7; j >= 5; --j) {
        const int T = 1 << (j - 5);     // 4, 2, 1
        const int tb = b * T;
        const float* contO = (j == 7) ? c7 : (j == 6) ? c6 : c5;
        const unsigned short* eIn = RG(j + 1);
        unsigned short* eOut = RG(j);

        {
            const unsigned short* src = eIn + (size_t)tb * 16384;
            #pragma unroll
            for (int it = 0; it < 4; ++it) {
                int q = t + it * 512;
                cp16_g2l(src + q * 8, &A_lds[0][0][0] + q * 8);
            }
            if (l4 == 0) {
                const float* p = contO + ((size_t)tb * 64 + wrow * 16 + l15) * 8;
                cO0 = *(const f32x4*)p; cO1 = *(const f32x4*)(p + 4);
            }
        }
        __syncthreads();

        for (int tt = 0; tt < T; ++tt) {
            const int tile = tb + tt;
            {
                bf16x8 cb = zeroA;
                if (l4 == 0) {
                    #pragma unroll
                    for (int e = 0; e < 4; ++e) {
                        ((unsigned short*)&cb)[e]     = f2bf(cO0[e]);
                        ((unsigned short*)&cb)[e + 4] = f2bf(cO1[e]);
                    }
                } else if (l4 == 1) cb = onesA;
                const int i = wrow * 16 + l15;
                __builtin_amdgcn_s_setprio(1);
                #pragma unroll
                for (int nfi = 0; nfi < 4; ++nfi) {
                    int nf = wcolh * 4 + nfi;
                    bf16x8 wv = zeroA;
                    if (l4 < 2) wv = *(const bf16x8*)&wu_lds[nf][l4 * 16 + l15][0];
                    f32x4 z = {0.f, 0.f, 0.f, 0.f};
                    z = __builtin_amdgcn_mfma_f32_16x16x32_bf16(wv, cb, z, 0, 0, 0);
                    u16x4 pk;
                    #pragma unroll
                    for (int r = 0; r < 4; ++r) pk[r] = f2bf(fmaxf(z[r], 0.f));
                    int n4 = nf * 16 + l4 * 4;
                    *(u16x4*)&u_lds[i][n4 ^ ((i & 15) << 3)] = pk;
                }
                __builtin_amdgcn_s_setprio(0);
            }
            {
                int tn = (tt + 1 < T) ? tile + 1 : tile;
                if (l4 == 0) {
                    const float* p = contO + ((size_t)tn * 64 + wrow * 16 + l15) * 8;
                    cO0 = *(const f32x4*)p; cO1 = *(const f32x4*)(p + 4);
                }
            }
            asm volatile("s_waitcnt vmcnt(6)" ::: "memory");  // drain 4 DMA; leave 4 stores + 2 loads
            asm volatile("s_waitcnt lgkmcnt(0)" ::: "memory");
            __builtin_amdgcn_sched_barrier(0);
            __builtin_amdgcn_s_barrier();
            __builtin_amdgcn_sched_barrier(0);

            f32x4 acc[4];
            #pragma unroll
            for (int mf = 0; mf < 4; ++mf) acc[mf] = bh4;
            __builtin_amdgcn_s_setprio(2);
            #pragma unroll
            for (int kb = 0; kb < 8; ++kb) {
                bf16x8 af[4];
                #pragma unroll
                for (int mf = 0; mf < 4; ++mf) {
                    int i = mf * 16 + l15;
                    af[mf] = *(const bf16x8*)&A_lds[kb >> 2][i][((((kb & 3) * 4) + l4) ^ (i & 15)) * 8];
                }
                #pragma unroll
                for (int mf = 0; mf < 4; ++mf)
                    acc[mf] = __builtin_amdgcn_mfma_f32_16x16x32_bf16(wreg[kb], af[mf], acc[mf], 0, 0, 0);
            }
            __builtin_amdgcn_s_setprio(0);
            asm volatile("s_waitcnt lgkmcnt(0)" ::: "memory");
            __builtin_amdgcn_sched_barrier(0);
            __builtin_amdgcn_s_barrier();
            __builtin_amdgcn_sched_barrier(0);
            if (tt + 1 < T) {
                const unsigned short* src = eIn + (size_t)(tile + 1) * 16384;
                #pragma unroll
                for (int it = 0; it < 4; ++it) {
                    int q = t + it * 512;
                    cp16_g2l(src + q * 8, &A_lds[0][0][0] + q * 8);
                }
            }
            __builtin_amdgcn_s_setprio(2);
            #pragma unroll
            for (int kb = 8; kb < 12; ++kb) {
                bf16x8 af[4];
                #pragma unroll
                for (int mf = 0; mf < 4; ++mf) {
                    int i = mf * 16 + l15;
                    af[mf] = *(const bf16x8*)&u_lds[i][((((kb - 8) * 4) + l4) ^ (i & 15)) * 8];
                }
                #pragma unroll
                for (int mf = 0; mf < 4; ++mf)
                    acc[mf] = __builtin_amdgcn_mfma_f32_16x16x32_bf16(wreg[kb], af[mf], acc[mf], 0, 0, 0);
            }
            __builtin_amdgcn_s_setprio(0);
            #pragma unroll
            for (int mf = 0; mf < 4; ++mf) {
                int i = mf * 16 + l15;
                int Rg = tile * 64 + i;
                int rr = Rg & 127, cc = rr & 1, il = rr >> 1;
                u16x4 pk;
                #pragma unroll
                for (int r = 0; r < 4; ++r) pk[r] = f2bf(fmaxf(acc[mf][r], 0.f));
                int n4 = wid * 16 + l4 * 4;
                *(u16x4*)&eOut[(size_t)(Rg >> 7) * 16384 + cc * 8192 + il * 128
                               + (n4 ^ ((il & 15) << 3))] = pk;
            }
            asm volatile("s_waitcnt lgkmcnt(0)" ::: "memory");
            __builtin_amdgcn_sched_barrier(0);
            __builtin_amdgcn_s_barrier();
        }
        asm volatile("s_waitcnt vmcnt(0) lgkmcnt(0)" ::: "memory");
        __builtin_amdgcn_sched_barrier(0);
        __builtin_amdgcn_s_barrier();
    }

    // ================= LEVELS 4..0: partial (reg-staged) =================
    for (int j = 4; j >= 0; --j) {
        const int R = 2 << j;            // 32..2
        const float* contO = (j == 4) ? c4 : (j == 3) ? c3 : (j == 2) ? c2
                           : (j == 1) ? c1 : c0;
        const unsigned short* eIn = RG(j + 1);
        unsigned short* eOut = (j > 0) ? RG(j) : nullptr;

        const size_t rowBase  = (size_t)b * (size_t)R;
        const size_t crowBase = rowBase * 2;

        {
            const int ilBase = ((int)(crowBase & 127)) >> 1;
            const unsigned short* gb = eIn + (crowBase >> 7) * (size_t)16384
                                     + (size_t)ilBase * 128;
            const int per = R * 16;
            for (int q = t; q < 2 * per; q += 512) {
                int cc = (q >= per) ? 1 : 0;
                int qq = q - cc * per;
                int il = qq >> 4, slot = qq & 15;
                int kc  = slot ^ (il & 15);
                int src = kc ^ ((ilBase + il) & 15);
                bf16x8 v = *(const bf16x8*)(gb + (size_t)cc * 8192 + il * 128 + src * 8);
                *(bf16x8*)&A_lds[cc][il][slot * 8] = v;
            }
        }
        {
            f32x4 a0 = {0,0,0,0}, a1 = {0,0,0,0};
            if (l4 == 0) {
                size_t row = rowBase + (size_t)(wrow * 16 + l15);
                size_t mx = rowBase + R - 1; if (row > mx) row = mx;
                const float* p = contO + row * 8;
                a0 = *(const f32x4*)p; a1 = *(const f32x4*)(p + 4);
            }
            bf16x8 cb = zeroA;
            if (l4 == 0) {
                #pragma unroll
                for (int e = 0; e < 4; ++e) {
                    ((unsigned short*)&cb)[e]     = f2bf(a0[e]);
                    ((unsigned short*)&cb)[e + 4] = f2bf(a1[e]);
                }
            } else if (l4 == 1) cb = onesA;
            const int i = wrow * 16 + l15;
            __builtin_amdgcn_s_setprio(1);
            #pragma unroll
            for (int nfi = 0; nfi < 4; ++nfi) {
                int nf = wcolh * 4 + nfi;
                bf16x8 wv = zeroA;
                if (l4 < 2) wv = *(const bf16x8*)&wu_lds[nf][l4 * 16 + l15][0];
                f32x4 z = {0.f, 0.f, 0.f, 0.f};
                z = __builtin_amdgcn_mfma_f32_16x16x32_bf16(wv, cb, z, 0, 0, 0);
                u16x4 pk;
                #pragma unroll
                for (int r = 0; r < 4; ++r) pk[r] = f2bf(fmaxf(z[r], 0.f));
                int n4 = nf * 16 + l4 * 4;
                *(u16x4*)&u_lds[i][n4 ^ ((i & 15) << 3)] = pk;
            }
            __builtin_amdgcn_s_setprio(0);
        }
        asm volatile("s_waitcnt lgkmcnt(0)" ::: "memory");
        __builtin_amdgcn_sched_barrier(0);
        __builtin_amdgcn_s_barrier();
        __builtin_amdgcn_sched_barrier(0);

        f32x4 acc[4];
        #pragma unroll
        for (int mf = 0; mf < 4; ++mf) acc[mf] = bh4;
        __builtin_amdgcn_s_setprio(2);
        #pragma unroll
        for (int kb = 0; kb < 8; ++kb) {
            bf16x8 af[4];
            #pragma unroll
            for (int mf = 0; mf < 4; ++mf) {
                int i = mf * 16 + l15;
                af[mf] = *(const bf16x8*)&A_lds[kb >> 2][i][((((kb & 3) * 4) + l4) ^ (i & 15)) * 8];
            }
            #pragma unroll
            for (int mf = 0; mf < 4; ++mf)
                acc[mf] = __builtin_amdgcn_mfma_f32_16x16x32_bf16(wreg[kb], af[mf], acc[mf], 0, 0, 0);
        }
        #pragma unroll
        for (int kb = 8; kb < 12; ++kb) {
            bf16x8 af[4];
            #pragma unroll
            for (int mf = 0; mf < 4; ++mf) {
                int i = mf * 16 + l15;
                af[mf] = *(const bf16x8*)&u_lds[i][((((kb - 8) * 4) + l4) ^ (i & 15)) * 8];
            }
            #pragma unroll
            for (int mf = 0; mf < 4; ++mf)
                acc[mf] = __builtin_amdgcn_mfma_f32_16x16x32_bf16(wreg[kb], af[mf], acc[mf], 0, 0, 0);
        }
        __builtin_amdgcn_s_setprio(0);
        if (j == 0) {
            #pragma unroll
            for (int mf = 0; mf < 4; ++mf) {
                int i = mf * 16 + l15;
                if (i < R) {
                    f32x4 o;
                    #pragma unroll
                    for (int r = 0; r < 4; ++r) o[r] = fmaxf(acc[mf][r], 0.f);
                    *(f32x4*)&outF[(rowBase + i) * 128 + wid * 16 + l4 * 4] = o;
                }
            }
        } else {
            #pragma unroll
            for (int mf = 0; mf < 4; ++mf) {
                int i = mf * 16 + l15;
                if (i < R) {
                    size_t Rg = rowBase + i;
                    int rr = (int)(Rg & 127), cc = rr & 1, il = rr >> 1;
                    u16x4 pk;
                    #pragma unroll
                    for (int r = 0; r < 4; ++r) pk[r] = f2bf(fmaxf(acc[mf][r], 0.f));
                    int n4 = wid * 16 + l4 * 4;
                    *(u16x4*)&eOut[(Rg >> 7) * 16384 + cc * 8192 + il * 128
                                   + (n4 ^ ((il & 15) << 3))] = pk;
                }
            }
        }
        asm volatile("s_waitcnt vmcnt(0) lgkmcnt(0)" ::: "memory");
        __builtin_amdgcn_sched_barrier(0);
        __builtin_amdgcn_s_barrier();
    }
    #undef RG
}

extern "C" void kernel_launch(void* const* d_in, const int* in_sizes, int n_in,
                              void* d_out, int out_size, void* d_ws, size_t ws_size,
                              hipStream_t stream) {
    const float* c[10];
    for (int j = 0; j < 10; ++j) c[j] = (const float*)d_in[j];
    const float* Wu = (const float*)d_in[19];
    const float* bu = (const float*)d_in[20];
    const float* Wh = (const float*)d_in[21];
    const float* bh = (const float*)d_in[22];

    unsigned short* Wbf   = (unsigned short*)d_ws;                       // 96 KiB (1 MiB pad)
    unsigned short* tbase = (unsigned short*)((char*)d_ws + (1u << 20)); // per-level regions

    k_cvtW<<<128, 384, 0, stream>>>(Wh, Wbf);
    k_main<<<512, 512, 0, stream>>>(c[0], c[1], c[2], c[3], c[4], c[5], c[6], c[7],
                                    c[8], c[9], Wbf, Wu, bu, bh, tbase, (float*)d_out);
}